// Round 2
// baseline (1447.627 us; speedup 1.0000x reference)
//
#include <hip/hip_runtime.h>
#include <cfloat>

// ---------------------------------------------------------------------------
// VectorQuantizer: z (16,256,32,32) f32, codebook (8192,256) f32
// outputs (concat as f32): z_q [4194304], loss [1], idx-as-float [16384]
//
// Reference semantics (numpy fp32): d = fl32(zsq + esq) - 2*dot32, argmin
// with lowest-index tie-break. Since esq <= 3.8e-6 < ulp(zsq)/2 (zsq ~ 256),
// fl32(zsq+esq) == zsq, so d = fl32(zsq - 2*dot32), quantized at ~1.5e-5.
// Ties are common (~6% of rows) and MUST break to the lowest index.
// d is invariant (up to a uniform grid shift) to which fp32 zsq we use, so
// zsq need not bit-match numpy's pairwise sum. Candidate dots are re-scored
// in fp64 -> fp32 in the fixup to minimize divergence from einsum's fp32 sum.
// ---------------------------------------------------------------------------

#define NROWS   16384        // 16 * 32 * 32
#define NCODE   8192
#define DIMC    256
#define HW      1024         // 32*32
#define ZQN     4194304      // 16*256*1024

// scratch layout inside d_out's z_q region (dead before zq_kernel overwrites):
#define ZSQ_OFF 0                       // 16384 floats (per-row fp32 |z|^2)
#define NSLICE  4
#define V1_OFF  16384                   // NSLICE*NROWS each
#define I1_OFF  (V1_OFF + NSLICE*NROWS)
#define V2_OFF  (I1_OFF + NSLICE*NROWS)
#define I2_OFF  (V2_OFF + NSLICE*NROWS) // ends at 278528 << 4194304
#define LOSS_OFF ZQN
#define IDX_OFF (ZQN + 1)

#define BM 128
#define BN 128
#define BD 32
#define KSLICE (NCODE / NSLICE)   // 2048
#define NTILES (KSLICE / BN)      // 16

__device__ __forceinline__ void top2_insert(float v, int i,
                                            float& w1, int& j1,
                                            float& w2, int& j2) {
    if (v < w1 || (v == w1 && i < j1)) { w2 = w1; j2 = j1; w1 = v; j1 = i; }
    else if (v < w2 || (v == w2 && i < j2)) { w2 = v; j2 = i; }
}

// --- 1: zsq[n] = fp32(sum_c z[n][c]^2), fp64-accumulated -------------------
__global__ void zsq_kernel(const float* __restrict__ z, float* __restrict__ buf) {
    int n = blockIdx.x * 256 + threadIdx.x;    // 64 blocks
    int b = n >> 10, hw = n & 1023;
    const float* zp = z + (size_t)b * (DIMC * HW) + hw;
    double s = 0.0;
    for (int c = 0; c < DIMC; ++c) {
        double v = (double)zp[(size_t)c * HW];   // coalesced across warp
        s += v * v;
    }
    buf[ZSQ_OFF + n] = (float)s;
}

// --- 2: tiled fp32 GEMM + per-row top-2 on (fl(zsq-2dot), idx) -------------
// grid: (NROWS/BM = 128, NSLICE = 4), block 256
__global__ __launch_bounds__(256, 2)
void argmin_kernel(const float* __restrict__ z, const float* __restrict__ cb,
                   float* __restrict__ buf) {
    __shared__ float smem[BD * BM + BD * BN + BM];   // a(4096) b(4096) zsq(128)
    float* a_s   = smem;
    float* b_s   = smem + BD * BM;
    float* zsq_s = smem + BD * BM + BD * BN;
    // merge-phase aliases (reuse a_s/b_s after compute is done; zsq_s intact):
    float* MV1 = smem;          // 2048 each
    float* MI1 = smem + 2048;
    float* MV2 = smem + 4096;
    float* MI2 = smem + 6144;

    int tid = threadIdx.x;
    int ty = tid >> 4, tx = tid & 15;
    int n0 = blockIdx.x * BM;
    int slice = blockIdx.y;
    int zb  = (n0 >> 10) * (DIMC * HW);
    int hw0 = n0 & (HW - 1);

    if (tid < BM) zsq_s[tid] = buf[ZSQ_OFF + n0 + tid];

    float v1[8], v2[8]; int i1[8], i2[8];
    #pragma unroll
    for (int r = 0; r < 8; ++r) { v1[r] = FLT_MAX; v2[r] = FLT_MAX; i1[r] = 0x7fffffff; i2[r] = 0x7fffffff; }

    for (int kt = 0; kt < NTILES; ++kt) {
        int k0 = slice * KSLICE + kt * BN;
        float acc[8][8];
        #pragma unroll
        for (int ri = 0; ri < 8; ++ri)
            #pragma unroll
            for (int ci = 0; ci < 8; ++ci) acc[ri][ci] = 0.f;

        for (int dt = 0; dt < DIMC / BD; ++dt) {
            int d0 = dt * BD;
            // stage z tile: a_s[d][r] = zf[n0+r][d0+d]   (coalesced float4)
            #pragma unroll
            for (int i = 0; i < 4; ++i) {
                int f = tid + i * 256;          // float4 index over 32x128
                int d = f >> 5, rq = f & 31;
                float4 v = *(const float4*)(z + zb + (size_t)(d0 + d) * HW + hw0 + rq * 4);
                *(float4*)(a_s + d * BM + rq * 4) = v;
            }
            // stage code tile transposed: b_s[d][j] = cb[k0+j][d0+d]
            #pragma unroll
            for (int i = 0; i < 4; ++i) {
                int f = tid + i * 256;          // float4 index over 128 codes x 8 quads
                int j = f >> 3, q = f & 7;
                float4 v = *(const float4*)(cb + (size_t)(k0 + j) * DIMC + d0 + q * 4);
                b_s[(q * 4 + 0) * BN + j] = v.x;
                b_s[(q * 4 + 1) * BN + j] = v.y;
                b_s[(q * 4 + 2) * BN + j] = v.z;
                b_s[(q * 4 + 3) * BN + j] = v.w;
            }
            __syncthreads();
            #pragma unroll
            for (int d = 0; d < BD; ++d) {
                float4 a0 = *(const float4*)(a_s + d * BM + ty * 8);
                float4 a1 = *(const float4*)(a_s + d * BM + ty * 8 + 4);
                float4 b0 = *(const float4*)(b_s + d * BN + tx * 4);
                float4 b1 = *(const float4*)(b_s + d * BN + 64 + tx * 4);
                float av[8] = {a0.x, a0.y, a0.z, a0.w, a1.x, a1.y, a1.z, a1.w};
                float bv[8] = {b0.x, b0.y, b0.z, b0.w, b1.x, b1.y, b1.z, b1.w};
                #pragma unroll
                for (int ri = 0; ri < 8; ++ri)
                    #pragma unroll
                    for (int ci = 0; ci < 8; ++ci)
                        acc[ri][ci] = fmaf(av[ri], bv[ci], acc[ri][ci]);
            }
            __syncthreads();
        }
        // epilogue: d = fl(zsq - 2*dot) (fma ok: 2*acc is exact), quantized ties
        #pragma unroll
        for (int ci = 0; ci < 8; ++ci) {
            int jj = (ci < 4) ? (tx * 4 + ci) : (64 + tx * 4 + ci - 4);
            int k = k0 + jj;
            #pragma unroll
            for (int ri = 0; ri < 8; ++ri) {
                float s = fmaf(-2.0f, acc[ri][ci], zsq_s[ty * 8 + ri]);
                top2_insert(s, k, v1[ri], i1[ri], v2[ri], i2[ri]);
            }
        }
        __syncthreads();   // protect a_s/b_s before next tile's staging
    }

    // block-level merge across tx (16 candidate-pairs per row)
    #pragma unroll
    for (int ri = 0; ri < 8; ++ri) {
        int m = (ty * 8 + ri) * 16 + tx;
        MV1[m] = v1[ri]; MI1[m] = __int_as_float(i1[ri]);
        MV2[m] = v2[ri]; MI2[m] = __int_as_float(i2[ri]);
    }
    __syncthreads();
    if (tid < BM) {
        float w1 = FLT_MAX, w2 = FLT_MAX; int j1 = 0x7fffffff, j2 = 0x7fffffff;
        for (int t = 0; t < 16; ++t) {
            int m = tid * 16 + t;
            top2_insert(MV1[m], __float_as_int(MI1[m]), w1, j1, w2, j2);
            top2_insert(MV2[m], __float_as_int(MI2[m]), w1, j1, w2, j2);
        }
        int o = slice * NROWS + n0 + tid;
        buf[V1_OFF + o] = w1;
        buf[I1_OFF + o] = __int_as_float(j1);
        buf[V2_OFF + o] = w2;
        buf[I2_OFF + o] = __int_as_float(j2);
    }
}

// --- 3: merge slices; re-score all 8 candidates with fp64 dot -> fp32 d ----
__global__ void fixup_kernel(const float* __restrict__ z, const float* __restrict__ cb,
                             float* __restrict__ out) {
    int n = blockIdx.x * 256 + threadIdx.x;
    float zsqv = out[ZSQ_OFF + n];
    int cand[8];
    #pragma unroll
    for (int s = 0; s < NSLICE; ++s) {
        int o = s * NROWS + n;
        cand[2 * s]     = __float_as_int(out[I1_OFF + o]);
        cand[2 * s + 1] = __float_as_int(out[I2_OFF + o]);
    }
    int b = n >> 10, hw = n & 1023;
    const float* zp = z + (size_t)b * (DIMC * HW) + hw;
    double acc[8];
    #pragma unroll
    for (int j = 0; j < 8; ++j) acc[j] = 0.0;
    for (int c = 0; c < DIMC; ++c) {
        double zc = (double)zp[(size_t)c * HW];   // coalesced across warp
        #pragma unroll
        for (int j = 0; j < 8; ++j)
            acc[j] += zc * (double)cb[(size_t)cand[j] * DIMC + c];
    }
    float bd = FLT_MAX; int bi = 0x7fffffff;
    #pragma unroll
    for (int j = 0; j < 8; ++j) {
        float t = (float)acc[j];                  // mimic einsum's fp32 output
        float d = fmaf(-2.0f, t, zsqv);           // fl(zsq - 2*t), exact mul
        int k = cand[j];
        if (d < bd || (d == bd && k < bi)) { bd = d; bi = k; }
    }
    out[IDX_OFF + n] = (float)bi;
}

// --- 4: z_q gather + squared-diff partial sums ------------------------------
__global__ void zq_kernel(const float* __restrict__ z, const float* __restrict__ cb,
                          float* __restrict__ out, float* __restrict__ partial) {
    int t0 = blockIdx.x * 256 + threadIdx.x;
    float lsum = 0.f;
    #pragma unroll
    for (int e = 0; e < 16; ++e) {
        int t = t0 + e * 262144;                 // flat (b,c,hw) index
        int c = (t >> 10) & 255;
        int n = ((t >> 18) << 10) | (t & 1023);
        int k = (int)out[IDX_OFF + n];           // idx stored as exact float
        float ev = cb[(size_t)k * DIMC + c];
        float zv = z[t];
        float d = ev - zv;
        lsum = fmaf(d, d, lsum);
        out[t] = ev;
    }
    #pragma unroll
    for (int off = 32; off; off >>= 1) lsum += __shfl_down(lsum, off);
    __shared__ float red[4];
    if ((threadIdx.x & 63) == 0) red[threadIdx.x >> 6] = lsum;
    __syncthreads();
    if (threadIdx.x == 0)
        partial[blockIdx.x] = red[0] + red[1] + red[2] + red[3];
}

// --- 5: final loss reduction ------------------------------------------------
__global__ void loss_kernel(const float* __restrict__ partial, float* __restrict__ out) {
    float s = 0.f;
    for (int i = threadIdx.x; i < 1024; i += 256) s += partial[i];
    #pragma unroll
    for (int off = 32; off; off >>= 1) s += __shfl_down(s, off);
    __shared__ float red[4];
    if ((threadIdx.x & 63) == 0) red[threadIdx.x >> 6] = s;
    __syncthreads();
    if (threadIdx.x == 0)
        out[LOSS_OFF] = 1.25f * (red[0] + red[1] + red[2] + red[3]) / 4194304.0f;
}

extern "C" void kernel_launch(void* const* d_in, const int* in_sizes, int n_in,
                              void* d_out, int out_size, void* d_ws, size_t ws_size,
                              hipStream_t stream) {
    const float* z  = (const float*)d_in[0];
    const float* cb = (const float*)d_in[1];
    float* out = (float*)d_out;
    float* partial = (float*)d_ws;   // 1024 floats (4 KB)

    zsq_kernel<<<NROWS / 256, 256, 0, stream>>>(z, out);
    argmin_kernel<<<dim3(NROWS / BM, NSLICE), 256, 0, stream>>>(z, cb, out);
    fixup_kernel<<<NROWS / 256, 256, 0, stream>>>(z, cb, out);
    zq_kernel<<<1024, 256, 0, stream>>>(z, cb, out, partial);
    loss_kernel<<<1, 256, 0, stream>>>(partial, out);
}

// Round 3
// 616.374 us; speedup vs baseline: 2.3486x; 2.3486x over previous
//
#include <hip/hip_runtime.h>
#include <cfloat>

// ---------------------------------------------------------------------------
// VectorQuantizer: z (16,256,32,32) f32, codebook (8192,256) f32
// outputs (f32 concat): z_q [4194304], loss [1], idx-as-float [16384]
// R2-validated semantics: idx = argmin_k fl32(zsq - 2*dot32(z,e_k)), lowest-
// index tie-break; candidates re-scored fp64->fp32 in fixup.
// R3: coarse pass = bf16 MFMA GEMM (error ~1.8e-6 << d-quantum 1.5e-5),
// top-2 per (lane-quad,slice) -> top-4 per (row, 1024-slice) -> 32 cands/row.
// ---------------------------------------------------------------------------

#define NROWS 16384
#define NCODE 8192
#define DIMC  256
#define HW    1024
#define ZQN   4194304

// scratch inside d_out's z_q region (all dead before zq_kernel overwrites):
#define ZT_OFF   0         // bf16 z, [16384][256], as ushort = 2097152 floats
#define CBT_OFF  2097152   // bf16 codebook [8192][256]       = 1048576 floats
#define ZSQ_OFF  3145728   // 16384 floats
#define CAND_OFF 3162112   // 8 slices * 16384 rows * 4 uints = 524288
#define LOSS_OFF ZQN
#define IDX_OFF  (ZQN + 1)

#define NSLICE 8

typedef __attribute__((ext_vector_type(8))) short bf16x8;
typedef __attribute__((ext_vector_type(4))) float f32x4;
typedef __attribute__((ext_vector_type(4))) unsigned int uint4v;

__device__ __forceinline__ unsigned umax(unsigned a, unsigned b) { return a > b ? a : b; }
__device__ __forceinline__ unsigned umin(unsigned a, unsigned b) { return a < b ? a : b; }

__device__ __forceinline__ unsigned short f2bf(float f) {   // RNE
    unsigned u = __float_as_uint(f);
    return (unsigned short)((u + 0x7fffu + ((u >> 16) & 1u)) >> 16);
}

#define GLD_LDS16(gptr, lptr) \
  __builtin_amdgcn_global_load_lds((const __attribute__((address_space(1))) unsigned int*)(const void*)(gptr), \
                                   (__attribute__((address_space(3))) unsigned int*)(lptr), 16, 0, 0)

// --- 1a: z (b,c,hw) f32 -> zt[n][c] bf16 (tiled transpose) ------------------
__global__ void zt_kernel(const float* __restrict__ z, float* __restrict__ out) {
    __shared__ unsigned short lds[64 * 65];
    unsigned short* zt = (unsigned short*)(out + ZT_OFF);
    int tid = threadIdx.x;
    int c0 = (blockIdx.x & 3) * 64;
    int n0 = (blockIdx.x >> 2) * 64;
    const float* zb = z + (size_t)(n0 >> 10) * (DIMC * HW) + (n0 & 1023);
    #pragma unroll
    for (int i = 0; i < 4; ++i) {
        int f = tid + i * 256;                 // 0..1023 over 64c x 16 n-quads
        int cl = f >> 4, n4 = f & 15;
        float4 v = *(const float4*)(zb + (size_t)(c0 + cl) * HW + n4 * 4);
        lds[(n4 * 4 + 0) * 65 + cl] = f2bf(v.x);
        lds[(n4 * 4 + 1) * 65 + cl] = f2bf(v.y);
        lds[(n4 * 4 + 2) * 65 + cl] = f2bf(v.z);
        lds[(n4 * 4 + 3) * 65 + cl] = f2bf(v.w);
    }
    __syncthreads();
    #pragma unroll
    for (int i = 0; i < 2; ++i) {
        int f = tid + i * 256;                 // 0..511 over 64n x 8 c-octs
        int nl = f >> 3, oct = f & 7;
        const unsigned short* p = lds + nl * 65 + oct * 8;
        uint4v u;
        u.x = (unsigned)p[0] | ((unsigned)p[1] << 16);
        u.y = (unsigned)p[2] | ((unsigned)p[3] << 16);
        u.z = (unsigned)p[4] | ((unsigned)p[5] << 16);
        u.w = (unsigned)p[6] | ((unsigned)p[7] << 16);
        *(uint4v*)(zt + (size_t)(n0 + nl) * DIMC + c0 + oct * 8) = u;
    }
}

// --- 1b: codebook f32 -> bf16 ----------------------------------------------
__global__ void cbt_kernel(const float* __restrict__ cb, float* __restrict__ out) {
    unsigned short* cbt = (unsigned short*)(out + CBT_OFF);
    size_t t = (size_t)blockIdx.x * 256 + threadIdx.x;
    float4 a = *(const float4*)(cb + t * 8);
    float4 b = *(const float4*)(cb + t * 8 + 4);
    uint4v u;
    u.x = (unsigned)f2bf(a.x) | ((unsigned)f2bf(a.y) << 16);
    u.y = (unsigned)f2bf(a.z) | ((unsigned)f2bf(a.w) << 16);
    u.z = (unsigned)f2bf(b.x) | ((unsigned)f2bf(b.y) << 16);
    u.w = (unsigned)f2bf(b.z) | ((unsigned)f2bf(b.w) << 16);
    *(uint4v*)(cbt + t * 8) = u;
}

// --- 1c: zsq[n] = fp32(sum z^2), fp64-accumulated --------------------------
__global__ void zsq_kernel(const float* __restrict__ z, float* __restrict__ out) {
    int n = blockIdx.x * 256 + threadIdx.x;
    const float* zp = z + (size_t)(n >> 10) * (DIMC * HW) + (n & 1023);
    double s = 0.0;
    for (int c = 0; c < DIMC; ++c) {
        double v = (double)zp[(size_t)c * HW];
        s += v * v;
    }
    out[ZSQ_OFF + n] = (float)s;
}

// --- 2: bf16 MFMA GEMM + packed top-2/lane, top-4/(row,slice) --------------
// grid (128 n-blocks, 8 slices), 256 threads. Block tile: 128 rows x 1024 codes.
__global__ __launch_bounds__(256, 3)
void argmin_kernel(float* __restrict__ out) {
    __shared__ __align__(16) unsigned short a_s[128 * 32];   // codes x d (8KB)
    __shared__ __align__(16) unsigned short b_s[128 * 32];   // rows  x d (8KB)
    __shared__ unsigned mg[2 * 128 * 4];                     // 4KB merge buf
    const unsigned short* zt  = (const unsigned short*)(out + ZT_OFF);
    const unsigned short* cbt = (const unsigned short*)(out + CBT_OFF);
    unsigned* cand = (unsigned*)(out + CAND_OFF);

    int tid = threadIdx.x;
    int lane = tid & 63;
    int wv = tid >> 6;                 // wave 0..3
    int wm = wv >> 1, wn = wv & 1;     // wave tile: codes 64 x rows 64
    int col = lane & 15, qk = lane >> 4;
    int n0 = blockIdx.x * 128;
    int slice = blockIdx.y;
    int k0 = slice * 1024;

    unsigned U1[4] = {0, 0, 0, 0}, U2[4] = {0, 0, 0, 0};   // packed top-2 per list

    for (int kt = 0; kt < 8; ++kt) {
        f32x4 acc[4][4];
        #pragma unroll
        for (int mi = 0; mi < 4; ++mi)
            #pragma unroll
            for (int ni = 0; ni < 4; ++ni)
                acc[mi][ni] = (f32x4){0.f, 0.f, 0.f, 0.f};
        int kbase = k0 + kt * 128;

        for (int dt = 0; dt < 8; ++dt) {
            __syncthreads();                       // prior reads of a_s/b_s done
            int dof = dt * 32 + (lane & 3) * 8;    // ushort offset in a 256-row
            int r16 = lane >> 2;
            #pragma unroll
            for (int c = 0; c < 4; ++c) {
                int chunk = wv * 4 + c;            // 0..15; 0-7=A, 8-15=B
                int c8 = chunk & 7;
                if (chunk < 8) {
                    GLD_LDS16(cbt + (size_t)(kbase + c8 * 16 + r16) * 256 + dof,
                              a_s + c8 * 512);
                } else {
                    GLD_LDS16(zt + (size_t)(n0 + c8 * 16 + r16) * 256 + dof,
                              b_s + c8 * 512);
                }
            }
            __syncthreads();                       // loads visible
            bf16x8 av[4], bv[4];
            #pragma unroll
            for (int mi = 0; mi < 4; ++mi)
                av[mi] = *(const bf16x8*)(a_s + (wm * 64 + mi * 16 + col) * 32 + qk * 8);
            #pragma unroll
            for (int ni = 0; ni < 4; ++ni)
                bv[ni] = *(const bf16x8*)(b_s + (wn * 64 + ni * 16 + col) * 32 + qk * 8);
            #pragma unroll
            for (int mi = 0; mi < 4; ++mi)
                #pragma unroll
                for (int ni = 0; ni < 4; ++ni)
                    acc[mi][ni] = __builtin_amdgcn_mfma_f32_16x16x32_bf16(
                        av[mi], bv[ni], acc[mi][ni], 0, 0, 0);
        }
        // epilogue: pack (score<<7 | kt,mi,r) and keep top-2 per list
        int ktag = kt << 4;
        #pragma unroll
        for (int ni = 0; ni < 4; ++ni) {
            #pragma unroll
            for (int mi = 0; mi < 4; ++mi) {
                #pragma unroll
                for (int r = 0; r < 4; ++r) {
                    float s = acc[mi][ni][r];
                    unsigned qv = (unsigned)fmaf(s, 2097152.0f, 131072.0f);
                    unsigned u = (qv << 7) | (unsigned)(ktag + mi * 4 + r);
                    unsigned lo = umin(u, U1[ni]);
                    U1[ni] = umax(u, U1[ni]);
                    U2[ni] = umax(lo, U2[ni]);
                }
            }
        }
    }

    // decode to (score<<10 | 1023-code_local), merge 4 quads -> top-4 set
    #pragma unroll
    for (int ni = 0; ni < 4; ++ni) {
        unsigned x1, x2;
        {
            unsigned t1 = U1[ni] & 127u;
            unsigned cl1 = ((t1 >> 4) << 7) + wm * 64 + (((t1 >> 2) & 3) << 4) + qk * 4 + (t1 & 3);
            x1 = ((U1[ni] >> 7) << 10) | (1023u - cl1);
            unsigned t2 = U2[ni] & 127u;
            unsigned cl2 = ((t2 >> 4) << 7) + wm * 64 + (((t2 >> 2) & 3) << 4) + qk * 4 + (t2 & 3);
            x2 = ((U2[ni] >> 7) << 10) | (1023u - cl2);
        }
        unsigned lo = umin(x1, x2); x1 = umax(x1, x2); x2 = lo;
        unsigned p1 = __shfl_xor(x1, 16);
        unsigned p2 = __shfl_xor(x2, 16);
        unsigned s1 = umax(x1, p1), tm = umin(x1, p1);
        unsigned ym = umax(x2, p2), s4 = umin(x2, p2);
        unsigned s2 = umax(tm, ym), s3 = umin(tm, ym);
        unsigned r1 = umax(s1, __shfl_xor(s4, 32));
        unsigned r2 = umax(s2, __shfl_xor(s3, 32));
        unsigned r3 = umax(s3, __shfl_xor(s2, 32));
        unsigned r4 = umax(s4, __shfl_xor(s1, 32));
        if (qk == 0) {
            int row = wn * 64 + ni * 16 + col;
            unsigned* m = mg + (wm * 128 + row) * 4;
            m[0] = r1; m[1] = r2; m[2] = r3; m[3] = r4;
        }
    }
    __syncthreads();
    if (tid < 128) {
        unsigned b0 = 0, b1 = 0, b2 = 0, b3 = 0;
        #pragma unroll
        for (int j = 0; j < 8; ++j) {
            unsigned u = mg[((j >> 2) * 128 + tid) * 4 + (j & 3)];
            unsigned m;
            m = umax(b0, u); u = umin(b0, u); b0 = m;
            m = umax(b1, u); u = umin(b1, u); b1 = m;
            m = umax(b2, u); u = umin(b2, u); b2 = m;
            b3 = umax(b3, u);
        }
        uint4v cw;
        cw.x = (unsigned)k0 + 1023u - (b0 & 1023u);
        cw.y = (unsigned)k0 + 1023u - (b1 & 1023u);
        cw.z = (unsigned)k0 + 1023u - (b2 & 1023u);
        cw.w = (unsigned)k0 + 1023u - (b3 & 1023u);
        *(uint4v*)(cand + ((size_t)slice * NROWS + n0 + tid) * 4) = cw;
    }
}

// --- 3: fp64 re-score of 32 candidates -> exact fp32 ranking, emit idx ------
__global__ void fixup_kernel(const float* __restrict__ z, const float* __restrict__ cb,
                             float* __restrict__ out) {
    int n = blockIdx.x * 64 + threadIdx.x;
    const unsigned* cand = (const unsigned*)(out + CAND_OFF);
    float zsqv = out[ZSQ_OFF + n];
    unsigned codes[32];
    #pragma unroll
    for (int s = 0; s < NSLICE; ++s) {
        uint4v c4 = *(const uint4v*)(cand + ((size_t)s * NROWS + n) * 4);
        codes[s * 4 + 0] = c4.x; codes[s * 4 + 1] = c4.y;
        codes[s * 4 + 2] = c4.z; codes[s * 4 + 3] = c4.w;
    }
    double acc[32];
    #pragma unroll
    for (int j = 0; j < 32; ++j) acc[j] = 0.0;
    const float* zp = z + (size_t)(n >> 10) * (DIMC * HW) + (n & 1023);
    for (int c = 0; c < DIMC; c += 4) {
        double z0 = (double)zp[(size_t)(c + 0) * HW];
        double z1 = (double)zp[(size_t)(c + 1) * HW];
        double z2 = (double)zp[(size_t)(c + 2) * HW];
        double z3 = (double)zp[(size_t)(c + 3) * HW];
        #pragma unroll
        for (int j = 0; j < 32; ++j) {
            float4 e = *(const float4*)(cb + (size_t)codes[j] * DIMC + c);
            acc[j] += z0 * (double)e.x + z1 * (double)e.y
                    + z2 * (double)e.z + z3 * (double)e.w;
        }
    }
    float bd = FLT_MAX; unsigned bi = 0xffffffffu;
    #pragma unroll
    for (int j = 0; j < 32; ++j) {
        float t = (float)acc[j];                 // mimic einsum's fp32 output
        float d = fmaf(-2.0f, t, zsqv);          // fl(zsq - 2*t)
        unsigned k = codes[j];
        if (d < bd || (d == bd && k < bi)) { bd = d; bi = k; }
    }
    out[IDX_OFF + n] = (float)bi;
}

// --- 4: z_q gather + squared-diff partial sums ------------------------------
__global__ void zq_kernel(const float* __restrict__ z, const float* __restrict__ cb,
                          float* __restrict__ out, float* __restrict__ partial) {
    int t0 = blockIdx.x * 256 + threadIdx.x;
    float lsum = 0.f;
    #pragma unroll
    for (int e = 0; e < 16; ++e) {
        int t = t0 + e * 262144;
        int c = (t >> 10) & 255;
        int n = ((t >> 18) << 10) | (t & 1023);
        int k = (int)out[IDX_OFF + n];
        float ev = cb[(size_t)k * DIMC + c];
        float zv = z[t];
        float d = ev - zv;
        lsum = fmaf(d, d, lsum);
        out[t] = ev;
    }
    #pragma unroll
    for (int off = 32; off; off >>= 1) lsum += __shfl_down(lsum, off);
    __shared__ float red[4];
    if ((threadIdx.x & 63) == 0) red[threadIdx.x >> 6] = lsum;
    __syncthreads();
    if (threadIdx.x == 0)
        partial[blockIdx.x] = red[0] + red[1] + red[2] + red[3];
}

// --- 5: final loss reduction ------------------------------------------------
__global__ void loss_kernel(const float* __restrict__ partial, float* __restrict__ out) {
    float s = 0.f;
    for (int i = threadIdx.x; i < 1024; i += 256) s += partial[i];
    #pragma unroll
    for (int off = 32; off; off >>= 1) s += __shfl_down(s, off);
    __shared__ float red[4];
    if ((threadIdx.x & 63) == 0) red[threadIdx.x >> 6] = s;
    __syncthreads();
    if (threadIdx.x == 0)
        out[LOSS_OFF] = 1.25f * (red[0] + red[1] + red[2] + red[3]) / 4194304.0f;
}

extern "C" void kernel_launch(void* const* d_in, const int* in_sizes, int n_in,
                              void* d_out, int out_size, void* d_ws, size_t ws_size,
                              hipStream_t stream) {
    const float* z  = (const float*)d_in[0];
    const float* cb = (const float*)d_in[1];
    float* out = (float*)d_out;
    float* partial = (float*)d_ws;   // 4 KB

    zt_kernel<<<1024, 256, 0, stream>>>(z, out);
    cbt_kernel<<<1024, 256, 0, stream>>>(cb, out);
    zsq_kernel<<<NROWS / 256, 256, 0, stream>>>(z, out);
    argmin_kernel<<<dim3(128, NSLICE), 256, 0, stream>>>(out);
    fixup_kernel<<<256, 64, 0, stream>>>(z, cb, out);
    zq_kernel<<<1024, 256, 0, stream>>>(z, cb, out, partial);
    loss_kernel<<<1, 256, 0, stream>>>(partial, out);
}

// Round 4
// 370.637 us; speedup vs baseline: 3.9058x; 1.6630x over previous
//
#include <hip/hip_runtime.h>
#include <cfloat>

// ---------------------------------------------------------------------------
// VectorQuantizer: z (16,256,32,32) f32, codebook (8192,256) f32
// outputs (f32 concat): z_q [4194304], loss [1], idx-as-float [16384]
// R2-validated semantics: idx = argmin_k fl32(zsq - 2*dot32(z,e_k)), lowest-
// index tie-break; candidates re-scored fp64->fp32 in fixup.
// R3: coarse pass = bf16 MFMA GEMM, 32 candidates/row. R4: fixup restructured
// from 1 thread/row (256 waves total, latency-starved, 326 us) to 1 thread
// per (row,candidate) with LDS-staged fp64 z rows (2048 blocks, ~25 us).
// ---------------------------------------------------------------------------

#define NROWS 16384
#define NCODE 8192
#define DIMC  256
#define HW    1024
#define ZQN   4194304

// scratch inside d_out's z_q region (all dead before zq_kernel overwrites):
#define ZT_OFF   0         // bf16 z, [16384][256], as ushort = 2097152 floats
#define CBT_OFF  2097152   // bf16 codebook [8192][256]       = 1048576 floats
#define ZSQ_OFF  3145728   // 16384 floats
#define CAND_OFF 3162112   // 8 slices * 16384 rows * 4 uints = 524288
#define LOSS_OFF ZQN
#define IDX_OFF  (ZQN + 1)

#define NSLICE 8

typedef __attribute__((ext_vector_type(8))) short bf16x8;
typedef __attribute__((ext_vector_type(4))) float f32x4;
typedef __attribute__((ext_vector_type(4))) unsigned int uint4v;

__device__ __forceinline__ unsigned umax(unsigned a, unsigned b) { return a > b ? a : b; }
__device__ __forceinline__ unsigned umin(unsigned a, unsigned b) { return a < b ? a : b; }

__device__ __forceinline__ unsigned short f2bf(float f) {   // RNE
    unsigned u = __float_as_uint(f);
    return (unsigned short)((u + 0x7fffu + ((u >> 16) & 1u)) >> 16);
}

#define GLD_LDS16(gptr, lptr) \
  __builtin_amdgcn_global_load_lds((const __attribute__((address_space(1))) unsigned int*)(const void*)(gptr), \
                                   (__attribute__((address_space(3))) unsigned int*)(lptr), 16, 0, 0)

// --- 1a: z (b,c,hw) f32 -> zt[n][c] bf16 (tiled transpose) ------------------
__global__ void zt_kernel(const float* __restrict__ z, float* __restrict__ out) {
    __shared__ unsigned short lds[64 * 65];
    unsigned short* zt = (unsigned short*)(out + ZT_OFF);
    int tid = threadIdx.x;
    int c0 = (blockIdx.x & 3) * 64;
    int n0 = (blockIdx.x >> 2) * 64;
    const float* zb = z + (size_t)(n0 >> 10) * (DIMC * HW) + (n0 & 1023);
    #pragma unroll
    for (int i = 0; i < 4; ++i) {
        int f = tid + i * 256;                 // 0..1023 over 64c x 16 n-quads
        int cl = f >> 4, n4 = f & 15;
        float4 v = *(const float4*)(zb + (size_t)(c0 + cl) * HW + n4 * 4);
        lds[(n4 * 4 + 0) * 65 + cl] = f2bf(v.x);
        lds[(n4 * 4 + 1) * 65 + cl] = f2bf(v.y);
        lds[(n4 * 4 + 2) * 65 + cl] = f2bf(v.z);
        lds[(n4 * 4 + 3) * 65 + cl] = f2bf(v.w);
    }
    __syncthreads();
    #pragma unroll
    for (int i = 0; i < 2; ++i) {
        int f = tid + i * 256;                 // 0..511 over 64n x 8 c-octs
        int nl = f >> 3, oct = f & 7;
        const unsigned short* p = lds + nl * 65 + oct * 8;
        uint4v u;
        u.x = (unsigned)p[0] | ((unsigned)p[1] << 16);
        u.y = (unsigned)p[2] | ((unsigned)p[3] << 16);
        u.z = (unsigned)p[4] | ((unsigned)p[5] << 16);
        u.w = (unsigned)p[6] | ((unsigned)p[7] << 16);
        *(uint4v*)(zt + (size_t)(n0 + nl) * DIMC + c0 + oct * 8) = u;
    }
}

// --- 1b: codebook f32 -> bf16 ----------------------------------------------
__global__ void cbt_kernel(const float* __restrict__ cb, float* __restrict__ out) {
    unsigned short* cbt = (unsigned short*)(out + CBT_OFF);
    size_t t = (size_t)blockIdx.x * 256 + threadIdx.x;
    float4 a = *(const float4*)(cb + t * 8);
    float4 b = *(const float4*)(cb + t * 8 + 4);
    uint4v u;
    u.x = (unsigned)f2bf(a.x) | ((unsigned)f2bf(a.y) << 16);
    u.y = (unsigned)f2bf(a.z) | ((unsigned)f2bf(a.w) << 16);
    u.z = (unsigned)f2bf(b.x) | ((unsigned)f2bf(b.y) << 16);
    u.w = (unsigned)f2bf(b.z) | ((unsigned)f2bf(b.w) << 16);
    *(uint4v*)(cbt + t * 8) = u;
}

// --- 1c: zsq[n] = fp32(sum z^2), fp64-accumulated --------------------------
__global__ void zsq_kernel(const float* __restrict__ z, float* __restrict__ out) {
    int n = blockIdx.x * 256 + threadIdx.x;
    const float* zp = z + (size_t)(n >> 10) * (DIMC * HW) + (n & 1023);
    double s = 0.0;
    for (int c = 0; c < DIMC; ++c) {
        double v = (double)zp[(size_t)c * HW];
        s += v * v;
    }
    out[ZSQ_OFF + n] = (float)s;
}

// --- 2: bf16 MFMA GEMM + packed top-2/lane, top-4/(row,slice) --------------
// grid (128 n-blocks, 8 slices), 256 threads. Block tile: 128 rows x 1024 codes.
__global__ __launch_bounds__(256, 3)
void argmin_kernel(float* __restrict__ out) {
    __shared__ __align__(16) unsigned short a_s[128 * 32];   // codes x d (8KB)
    __shared__ __align__(16) unsigned short b_s[128 * 32];   // rows  x d (8KB)
    __shared__ unsigned mg[2 * 128 * 4];                     // 4KB merge buf
    const unsigned short* zt  = (const unsigned short*)(out + ZT_OFF);
    const unsigned short* cbt = (const unsigned short*)(out + CBT_OFF);
    unsigned* cand = (unsigned*)(out + CAND_OFF);

    int tid = threadIdx.x;
    int lane = tid & 63;
    int wv = tid >> 6;                 // wave 0..3
    int wm = wv >> 1, wn = wv & 1;     // wave tile: codes 64 x rows 64
    int col = lane & 15, qk = lane >> 4;
    int n0 = blockIdx.x * 128;
    int slice = blockIdx.y;
    int k0 = slice * 1024;

    unsigned U1[4] = {0, 0, 0, 0}, U2[4] = {0, 0, 0, 0};   // packed top-2 per list

    for (int kt = 0; kt < 8; ++kt) {
        f32x4 acc[4][4];
        #pragma unroll
        for (int mi = 0; mi < 4; ++mi)
            #pragma unroll
            for (int ni = 0; ni < 4; ++ni)
                acc[mi][ni] = (f32x4){0.f, 0.f, 0.f, 0.f};
        int kbase = k0 + kt * 128;

        for (int dt = 0; dt < 8; ++dt) {
            __syncthreads();                       // prior reads of a_s/b_s done
            int dof = dt * 32 + (lane & 3) * 8;    // ushort offset in a 256-row
            int r16 = lane >> 2;
            #pragma unroll
            for (int c = 0; c < 4; ++c) {
                int chunk = wv * 4 + c;            // 0..15; 0-7=A, 8-15=B
                int c8 = chunk & 7;
                if (chunk < 8) {
                    GLD_LDS16(cbt + (size_t)(kbase + c8 * 16 + r16) * 256 + dof,
                              a_s + c8 * 512);
                } else {
                    GLD_LDS16(zt + (size_t)(n0 + c8 * 16 + r16) * 256 + dof,
                              b_s + c8 * 512);
                }
            }
            __syncthreads();                       // loads visible
            bf16x8 av[4], bv[4];
            #pragma unroll
            for (int mi = 0; mi < 4; ++mi)
                av[mi] = *(const bf16x8*)(a_s + (wm * 64 + mi * 16 + col) * 32 + qk * 8);
            #pragma unroll
            for (int ni = 0; ni < 4; ++ni)
                bv[ni] = *(const bf16x8*)(b_s + (wn * 64 + ni * 16 + col) * 32 + qk * 8);
            #pragma unroll
            for (int mi = 0; mi < 4; ++mi)
                #pragma unroll
                for (int ni = 0; ni < 4; ++ni)
                    acc[mi][ni] = __builtin_amdgcn_mfma_f32_16x16x32_bf16(
                        av[mi], bv[ni], acc[mi][ni], 0, 0, 0);
        }
        // epilogue: pack (score<<7 | kt,mi,r) and keep top-2 per list
        int ktag = kt << 4;
        #pragma unroll
        for (int ni = 0; ni < 4; ++ni) {
            #pragma unroll
            for (int mi = 0; mi < 4; ++mi) {
                #pragma unroll
                for (int r = 0; r < 4; ++r) {
                    float s = acc[mi][ni][r];
                    unsigned qv = (unsigned)fmaf(s, 2097152.0f, 131072.0f);
                    unsigned u = (qv << 7) | (unsigned)(ktag + mi * 4 + r);
                    unsigned lo = umin(u, U1[ni]);
                    U1[ni] = umax(u, U1[ni]);
                    U2[ni] = umax(lo, U2[ni]);
                }
            }
        }
    }

    // decode to (score<<10 | 1023-code_local), merge 4 quads -> top-4 set
    #pragma unroll
    for (int ni = 0; ni < 4; ++ni) {
        unsigned x1, x2;
        {
            unsigned t1 = U1[ni] & 127u;
            unsigned cl1 = ((t1 >> 4) << 7) + wm * 64 + (((t1 >> 2) & 3) << 4) + qk * 4 + (t1 & 3);
            x1 = ((U1[ni] >> 7) << 10) | (1023u - cl1);
            unsigned t2 = U2[ni] & 127u;
            unsigned cl2 = ((t2 >> 4) << 7) + wm * 64 + (((t2 >> 2) & 3) << 4) + qk * 4 + (t2 & 3);
            x2 = ((U2[ni] >> 7) << 10) | (1023u - cl2);
        }
        unsigned lo = umin(x1, x2); x1 = umax(x1, x2); x2 = lo;
        unsigned p1 = __shfl_xor(x1, 16);
        unsigned p2 = __shfl_xor(x2, 16);
        unsigned s1 = umax(x1, p1), tm = umin(x1, p1);
        unsigned ym = umax(x2, p2), s4 = umin(x2, p2);
        unsigned s2 = umax(tm, ym), s3 = umin(tm, ym);
        unsigned r1 = umax(s1, __shfl_xor(s4, 32));
        unsigned r2 = umax(s2, __shfl_xor(s3, 32));
        unsigned r3 = umax(s3, __shfl_xor(s2, 32));
        unsigned r4 = umax(s4, __shfl_xor(s1, 32));
        if (qk == 0) {
            int row = wn * 64 + ni * 16 + col;
            unsigned* m = mg + (wm * 128 + row) * 4;
            m[0] = r1; m[1] = r2; m[2] = r3; m[3] = r4;
        }
    }
    __syncthreads();
    if (tid < 128) {
        unsigned b0 = 0, b1 = 0, b2 = 0, b3 = 0;
        #pragma unroll
        for (int j = 0; j < 8; ++j) {
            unsigned u = mg[((j >> 2) * 128 + tid) * 4 + (j & 3)];
            unsigned m;
            m = umax(b0, u); u = umin(b0, u); b0 = m;
            m = umax(b1, u); u = umin(b1, u); b1 = m;
            m = umax(b2, u); u = umin(b2, u); b2 = m;
            b3 = umax(b3, u);
        }
        uint4v cw;
        cw.x = (unsigned)k0 + 1023u - (b0 & 1023u);
        cw.y = (unsigned)k0 + 1023u - (b1 & 1023u);
        cw.z = (unsigned)k0 + 1023u - (b2 & 1023u);
        cw.w = (unsigned)k0 + 1023u - (b3 & 1023u);
        *(uint4v*)(cand + ((size_t)slice * NROWS + n0 + tid) * 4) = cw;
    }
}

// --- 3: fp64 re-score, one thread per (row,candidate) ----------------------
// grid 2048 blocks x 256 threads; block = 8 rows x 32 candidates.
__global__ __launch_bounds__(256, 4)
void fixup_kernel(const float* __restrict__ z, const float* __restrict__ cb,
                  float* __restrict__ out) {
    __shared__ double zd[DIMC * 8];      // z rows as fp64, [c][r]  (16 KB)
    __shared__ float zsq_s[8];
    __shared__ float dsc[32 * 8];
    __shared__ unsigned cds[32 * 8];
    int tid = threadIdx.x;
    int n0 = blockIdx.x * 8;
    const float* zb = z + (size_t)(n0 >> 10) * (DIMC * HW) + (n0 & 1023);
    int rr = tid & 7;
    #pragma unroll
    for (int i = 0; i < 8; ++i) {
        int c = (tid >> 3) + i * 32;     // contiguous 8-float segments per c
        zd[c * 8 + rr] = (double)zb[(size_t)c * HW + rr];
    }
    if (tid < 8) zsq_s[tid] = out[ZSQ_OFF + n0 + tid];
    int j = tid >> 3, r = tid & 7;       // candidate j in [0,32), row r in [0,8)
    unsigned code = ((const unsigned*)(out + CAND_OFF))
                    [(((size_t)(j >> 2)) * NROWS + n0 + r) * 4 + (j & 3)];
    __syncthreads();
    const float* e = cb + (size_t)code * DIMC;
    double acc = 0.0;
    for (int c = 0; c < DIMC; c += 4) {
        float4 ev = *(const float4*)(e + c);      // contiguous per thread
        acc += zd[(c + 0) * 8 + r] * (double)ev.x
             + zd[(c + 1) * 8 + r] * (double)ev.y
             + zd[(c + 2) * 8 + r] * (double)ev.z
             + zd[(c + 3) * 8 + r] * (double)ev.w;
    }
    float d = fmaf(-2.0f, (float)acc, zsq_s[r]);  // fl(zsq - 2*dot)
    dsc[j * 8 + r] = d;
    cds[j * 8 + r] = code;
    __syncthreads();
    if (tid < 8) {
        float bd = FLT_MAX; unsigned bi = 0xffffffffu;
        for (int jj = 0; jj < 32; ++jj) {
            float dv = dsc[jj * 8 + tid];
            unsigned k = cds[jj * 8 + tid];
            if (dv < bd || (dv == bd && k < bi)) { bd = dv; bi = k; }
        }
        out[IDX_OFF + n0 + tid] = (float)bi;
    }
}

// --- 4: z_q gather + squared-diff partial sums ------------------------------
__global__ void zq_kernel(const float* __restrict__ z, const float* __restrict__ cb,
                          float* __restrict__ out, float* __restrict__ partial) {
    int t0 = blockIdx.x * 256 + threadIdx.x;
    float lsum = 0.f;
    #pragma unroll
    for (int e = 0; e < 16; ++e) {
        int t = t0 + e * 262144;
        int c = (t >> 10) & 255;
        int n = ((t >> 18) << 10) | (t & 1023);
        int k = (int)out[IDX_OFF + n];
        float ev = cb[(size_t)k * DIMC + c];
        float zv = z[t];
        float d = ev - zv;
        lsum = fmaf(d, d, lsum);
        out[t] = ev;
    }
    #pragma unroll
    for (int off = 32; off; off >>= 1) lsum += __shfl_down(lsum, off);
    __shared__ float red[4];
    if ((threadIdx.x & 63) == 0) red[threadIdx.x >> 6] = lsum;
    __syncthreads();
    if (threadIdx.x == 0)
        partial[blockIdx.x] = red[0] + red[1] + red[2] + red[3];
}

// --- 5: final loss reduction ------------------------------------------------
__global__ void loss_kernel(const float* __restrict__ partial, float* __restrict__ out) {
    float s = 0.f;
    for (int i = threadIdx.x; i < 1024; i += 256) s += partial[i];
    #pragma unroll
    for (int off = 32; off; off >>= 1) s += __shfl_down(s, off);
    __shared__ float red[4];
    if ((threadIdx.x & 63) == 0) red[threadIdx.x >> 6] = s;
    __syncthreads();
    if (threadIdx.x == 0)
        out[LOSS_OFF] = 1.25f * (red[0] + red[1] + red[2] + red[3]) / 4194304.0f;
}

extern "C" void kernel_launch(void* const* d_in, const int* in_sizes, int n_in,
                              void* d_out, int out_size, void* d_ws, size_t ws_size,
                              hipStream_t stream) {
    const float* z  = (const float*)d_in[0];
    const float* cb = (const float*)d_in[1];
    float* out = (float*)d_out;
    float* partial = (float*)d_ws;   // 4 KB

    zt_kernel<<<1024, 256, 0, stream>>>(z, out);
    cbt_kernel<<<1024, 256, 0, stream>>>(cb, out);
    zsq_kernel<<<NROWS / 256, 256, 0, stream>>>(z, out);
    argmin_kernel<<<dim3(128, NSLICE), 256, 0, stream>>>(out);
    fixup_kernel<<<NROWS / 8, 256, 0, stream>>>(z, cb, out);
    zq_kernel<<<1024, 256, 0, stream>>>(z, cb, out, partial);
    loss_kernel<<<1, 256, 0, stream>>>(partial, out);
}

// Round 5
// 235.615 us; speedup vs baseline: 6.1440x; 1.5731x over previous
//
#include <hip/hip_runtime.h>
#include <cfloat>

// ---------------------------------------------------------------------------
// VectorQuantizer: z (16,256,32,32) f32, codebook (8192,256) f32
// outputs (f32 concat): z_q [4194304], loss [1], idx-as-float [16384]
// Validated semantics (R2-R4): idx = argmin_k fl32(zsq - 2*dot32(z,e_k)),
// lowest-index tie-break; bf16-MFMA coarse top-4 x 8 slices -> 32 cands/row,
// re-scored fp64->fp32 in fixup.
// R5: argmin rebuilt: z-rows in registers (loaded once), codes streamed via
// 16KB swizzled LDS buffer, 32 MFMA/barrier, in-register shfl merge.
// zq rebuilt: LDS-staged codebook rows (coalesced) instead of 4B gathers.
// ---------------------------------------------------------------------------

#define NROWS 16384
#define NCODE 8192
#define DIMC  256
#define HW    1024
#define ZQN   4194304

// scratch inside d_out's z_q region (dead before zq_kernel overwrites):
#define ZT_OFF   0         // bf16 z [16384][256] as ushort = 2097152 floats
#define CBT_OFF  2097152   // bf16 codebook [8192][256]     = 1048576 floats
#define ZSQ_OFF  3145728   // 16384 floats
#define CAND_OFF 3162112   // 8 slices * 16384 rows * 4 uints (ends 3686400)
#define LOSS_OFF ZQN
#define IDX_OFF  (ZQN + 1)

#define NSLICE 8

typedef __attribute__((ext_vector_type(8))) short bf16x8;
typedef __attribute__((ext_vector_type(4))) float f32x4;
typedef __attribute__((ext_vector_type(4))) unsigned int uint4v;

__device__ __forceinline__ unsigned umax(unsigned a, unsigned b) { return a > b ? a : b; }
__device__ __forceinline__ unsigned umin(unsigned a, unsigned b) { return a < b ? a : b; }

__device__ __forceinline__ unsigned short f2bf(float f) {   // RNE
    unsigned u = __float_as_uint(f);
    return (unsigned short)((u + 0x7fffu + ((u >> 16) & 1u)) >> 16);
}

#define GLD_LDS16(gptr, lptr) \
  __builtin_amdgcn_global_load_lds((const __attribute__((address_space(1))) unsigned int*)(const void*)(gptr), \
                                   (__attribute__((address_space(3))) unsigned int*)(lptr), 16, 0, 0)

// --- 1: fused prep: zt transpose+cvt | cbt cvt | zsq ------------------------
__global__ void prep_kernel(const float* __restrict__ z, const float* __restrict__ cb,
                            float* __restrict__ out) {
    int bid = blockIdx.x;
    int tid = threadIdx.x;
    if (bid < 1024) {
        // z (b,c,hw) f32 -> zt[n][c] bf16, tiled transpose
        __shared__ unsigned short lds[64 * 65];
        unsigned short* zt = (unsigned short*)(out + ZT_OFF);
        int c0 = (bid & 3) * 64;
        int n0 = (bid >> 2) * 64;
        const float* zb = z + (size_t)(n0 >> 10) * (DIMC * HW) + (n0 & 1023);
        #pragma unroll
        for (int i = 0; i < 4; ++i) {
            int f = tid + i * 256;
            int cl = f >> 4, n4 = f & 15;
            float4 v = *(const float4*)(zb + (size_t)(c0 + cl) * HW + n4 * 4);
            lds[(n4 * 4 + 0) * 65 + cl] = f2bf(v.x);
            lds[(n4 * 4 + 1) * 65 + cl] = f2bf(v.y);
            lds[(n4 * 4 + 2) * 65 + cl] = f2bf(v.z);
            lds[(n4 * 4 + 3) * 65 + cl] = f2bf(v.w);
        }
        __syncthreads();
        #pragma unroll
        for (int i = 0; i < 2; ++i) {
            int f = tid + i * 256;
            int nl = f >> 3, oct = f & 7;
            const unsigned short* p = lds + nl * 65 + oct * 8;
            uint4v u;
            u.x = (unsigned)p[0] | ((unsigned)p[1] << 16);
            u.y = (unsigned)p[2] | ((unsigned)p[3] << 16);
            u.z = (unsigned)p[4] | ((unsigned)p[5] << 16);
            u.w = (unsigned)p[6] | ((unsigned)p[7] << 16);
            *(uint4v*)(zt + (size_t)(n0 + nl) * DIMC + c0 + oct * 8) = u;
        }
    } else if (bid < 2048) {
        unsigned short* cbt = (unsigned short*)(out + CBT_OFF);
        size_t t = (size_t)(bid - 1024) * 256 + tid;
        float4 a = *(const float4*)(cb + t * 8);
        float4 b = *(const float4*)(cb + t * 8 + 4);
        uint4v u;
        u.x = (unsigned)f2bf(a.x) | ((unsigned)f2bf(a.y) << 16);
        u.y = (unsigned)f2bf(a.z) | ((unsigned)f2bf(a.w) << 16);
        u.z = (unsigned)f2bf(b.x) | ((unsigned)f2bf(b.y) << 16);
        u.w = (unsigned)f2bf(b.z) | ((unsigned)f2bf(b.w) << 16);
        *(uint4v*)(cbt + t * 8) = u;
    } else {
        int n = (bid - 2048) * 256 + tid;
        const float* zp = z + (size_t)(n >> 10) * (DIMC * HW) + (n & 1023);
        double s = 0.0;
        for (int c = 0; c < DIMC; ++c) {
            double v = (double)zp[(size_t)c * HW];
            s += v * v;
        }
        out[ZSQ_OFF + n] = (float)s;
    }
}

// --- 2: bf16 MFMA argmin: z-rows in registers, codes streamed ---------------
// grid (128 row-blocks, 8 slices), 256 threads. Block: 128 rows x 1024 codes.
__global__ __launch_bounds__(256, 4)
void argmin_kernel(float* __restrict__ out) {
    __shared__ __align__(16) unsigned short a_s[32 * 256];   // 16 KB code chunk
    const unsigned short* zt  = (const unsigned short*)(out + ZT_OFF);
    const unsigned short* cbt = (const unsigned short*)(out + CBT_OFF);
    unsigned* cand = (unsigned*)(out + CAND_OFF);

    int tid = threadIdx.x;
    int lane = tid & 63;
    int wv = tid >> 6;
    int col = lane & 15, qk = lane >> 4;
    int n0 = blockIdx.x * 128;
    int slice = blockIdx.y;

    // B: this wave's 32 z-rows resident in registers (2 rowfrags x 8 dsteps)
    bf16x8 B[2][8];
    #pragma unroll
    for (int rf = 0; rf < 2; ++rf)
        #pragma unroll
        for (int t = 0; t < 8; ++t)
            B[rf][t] = *(const bf16x8*)(zt + (size_t)(n0 + wv * 32 + rf * 16 + col) * DIMC
                                           + t * 32 + qk * 8);

    // staging source: lane covers (row pair, 16B slot), XOR-swizzled slot
    int rl2 = lane >> 5;            // which of 2 rows in this GLD inst
    int jsl = lane & 31;            // dest 16B slot within a 512B row
    const unsigned short* srcb[4];
    #pragma unroll
    for (int c = 0; c < 4; ++c) {
        int rloc = (wv * 4 + c) * 2 + rl2;                    // code row 0..31
        int src16 = jsl ^ (rloc & 7);                         // source 16B chunk
        srcb[c] = cbt + ((size_t)slice * 1024 + rloc) * DIMC + src16 * 8;
    }

    unsigned U1[2] = {0, 0}, U2[2] = {0, 0};   // packed top-2 per rowfrag list

    for (int ch = 0; ch < 32; ++ch) {
        __syncthreads();                       // prior chunk's reads done
        #pragma unroll
        for (int c = 0; c < 4; ++c)
            GLD_LDS16(srcb[c] + (size_t)ch * 32 * DIMC, a_s + (wv * 4 + c) * 512);
        __syncthreads();                       // staged data visible

        f32x4 acc[2][2];
        #pragma unroll
        for (int rf = 0; rf < 2; ++rf)
            #pragma unroll
            for (int cf = 0; cf < 2; ++cf)
                acc[rf][cf] = (f32x4){0.f, 0.f, 0.f, 0.f};
        #pragma unroll
        for (int cf = 0; cf < 2; ++cf) {
            int rloc = cf * 16 + col;
            #pragma unroll
            for (int t = 0; t < 8; ++t) {
                bf16x8 af = *(const bf16x8*)(a_s + rloc * 256
                                             + ((unsigned)((qk + 4 * t) ^ (rloc & 7))) * 8);
                acc[0][cf] = __builtin_amdgcn_mfma_f32_16x16x32_bf16(af, B[0][t], acc[0][cf], 0, 0, 0);
                acc[1][cf] = __builtin_amdgcn_mfma_f32_16x16x32_bf16(af, B[1][t], acc[1][cf], 0, 0, 0);
            }
        }
        // epilogue: pack (qv<<8 | 255-tag), keep top-2 per rowfrag
        #pragma unroll
        for (int rf = 0; rf < 2; ++rf)
            #pragma unroll
            for (int cf = 0; cf < 2; ++cf)
                #pragma unroll
                for (int r = 0; r < 4; ++r) {
                    float s = acc[rf][cf][r];
                    unsigned qv = (unsigned)fmaf(s, 2097152.0f, 131072.0f);
                    unsigned u = (qv << 8) | (255u - (unsigned)((ch << 3) | (cf << 2) | r));
                    unsigned lo = umin(u, U1[rf]);
                    U1[rf] = umax(u, U1[rf]);
                    U2[rf] = umax(lo, U2[rf]);
                }
    }

    // decode + cross-lane (qk) merge to top-4 per row, write candidates
    #pragma unroll
    for (int rf = 0; rf < 2; ++rf) {
        unsigned t1 = 255u - (U1[rf] & 255u);
        unsigned c1 = (t1 >> 3) * 32 + ((t1 >> 2) & 1) * 16 + qk * 4 + (t1 & 3);
        unsigned x1 = ((U1[rf] >> 8) << 10) | (1023u - c1);
        unsigned t2 = 255u - (U2[rf] & 255u);
        unsigned c2 = (t2 >> 3) * 32 + ((t2 >> 2) & 1) * 16 + qk * 4 + (t2 & 3);
        unsigned x2 = ((U2[rf] >> 8) << 10) | (1023u - c2);
        // merge sorted pairs across qk^1, then top-4 across qk^2 (bitonic)
        unsigned p1 = __shfl_xor(x1, 16);
        unsigned p2 = __shfl_xor(x2, 16);
        unsigned s1 = umax(x1, p1), tm = umin(x1, p1);
        unsigned ym = umax(x2, p2), s4 = umin(x2, p2);
        unsigned s2 = umax(tm, ym), s3 = umin(tm, ym);
        unsigned r1 = umax(s1, __shfl_xor(s4, 32));
        unsigned r2 = umax(s2, __shfl_xor(s3, 32));
        unsigned r3 = umax(s3, __shfl_xor(s2, 32));
        unsigned r4 = umax(s4, __shfl_xor(s1, 32));
        if (qk == 0) {
            int row = wv * 32 + rf * 16 + col;
            unsigned k0 = (unsigned)(slice * 1024);
            uint4v cw;
            cw.x = k0 + 1023u - (r1 & 1023u);
            cw.y = k0 + 1023u - (r2 & 1023u);
            cw.z = k0 + 1023u - (r3 & 1023u);
            cw.w = k0 + 1023u - (r4 & 1023u);
            *(uint4v*)(cand + ((size_t)slice * NROWS + n0 + row) * 4) = cw;
        }
    }
}

// --- 3: fp64 re-score, one thread per (row,candidate) ----------------------
__global__ __launch_bounds__(256, 4)
void fixup_kernel(const float* __restrict__ z, const float* __restrict__ cb,
                  float* __restrict__ out) {
    __shared__ double zd[DIMC * 8];
    __shared__ float zsq_s[8];
    __shared__ float dsc[32 * 8];
    __shared__ unsigned cds[32 * 8];
    int tid = threadIdx.x;
    int n0 = blockIdx.x * 8;
    const float* zb = z + (size_t)(n0 >> 10) * (DIMC * HW) + (n0 & 1023);
    int rr = tid & 7;
    #pragma unroll
    for (int i = 0; i < 8; ++i) {
        int c = (tid >> 3) + i * 32;
        zd[c * 8 + rr] = (double)zb[(size_t)c * HW + rr];
    }
    if (tid < 8) zsq_s[tid] = out[ZSQ_OFF + n0 + tid];
    int j = tid >> 3, r = tid & 7;
    unsigned code = ((const unsigned*)(out + CAND_OFF))
                    [(((size_t)(j >> 2)) * NROWS + n0 + r) * 4 + (j & 3)];
    __syncthreads();
    const float* e = cb + (size_t)code * DIMC;
    double acc = 0.0;
    for (int c = 0; c < DIMC; c += 4) {
        float4 ev = *(const float4*)(e + c);
        acc += zd[(c + 0) * 8 + r] * (double)ev.x
             + zd[(c + 1) * 8 + r] * (double)ev.y
             + zd[(c + 2) * 8 + r] * (double)ev.z
             + zd[(c + 3) * 8 + r] * (double)ev.w;
    }
    float d = fmaf(-2.0f, (float)acc, zsq_s[r]);
    dsc[j * 8 + r] = d;
    cds[j * 8 + r] = code;
    __syncthreads();
    if (tid < 8) {
        float bd = FLT_MAX; unsigned bi = 0xffffffffu;
        for (int jj = 0; jj < 32; ++jj) {
            float dv = dsc[jj * 8 + tid];
            unsigned k = cds[jj * 8 + tid];
            if (dv < bd || (dv == bd && k < bi)) { bd = dv; bi = k; }
        }
        out[IDX_OFF + n0 + tid] = (float)bi;
    }
}

// --- 4: z_q via LDS-staged codebook rows + loss partials --------------------
// 256 blocks x 256 threads; block = 64 rows (one b, hw0..hw0+63)
__global__ void zq_kernel(const float* __restrict__ z, const float* __restrict__ cb,
                          float* __restrict__ out, float* __restrict__ partial) {
    __shared__ float lds[64 * 256];            // 64 KB, 16B-chunk XOR swizzle
    int tid = threadIdx.x;
    int n0 = blockIdx.x * 64;
    // stage: 4 threads per row, each loads 64 consecutive floats of cb row
    {
        int r = tid >> 2, q = tid & 3;
        int code = (int)out[IDX_OFF + n0 + r];
        const float* e = cb + (size_t)code * DIMC + q * 64;
        #pragma unroll
        for (int i = 0; i < 16; ++i) {
            float4 v = *(const float4*)(e + i * 4);
            int c4 = q * 16 + i;
            *(float4*)(lds + r * 256 + ((c4 ^ (r & 7)) * 4)) = v;
        }
    }
    __syncthreads();
    // write-out + loss: lanes scan hw (coalesced), 4 c-groups across block
    int hwl = tid & 63, g = tid >> 6;
    int b = n0 >> 10, hw0 = n0 & 1023;
    const size_t obase = (size_t)b * (DIMC * HW) + hw0 + hwl;
    float lsum = 0.f;
    #pragma unroll
    for (int i = 0; i < 16; ++i) {
        int c4 = g * 16 + i;
        float4 v = *(const float4*)(lds + hwl * 256 + ((c4 ^ (hwl & 7)) * 4));
        int c0 = c4 * 4;
        float z0 = z[obase + (size_t)(c0 + 0) * HW];
        float z1 = z[obase + (size_t)(c0 + 1) * HW];
        float z2 = z[obase + (size_t)(c0 + 2) * HW];
        float z3 = z[obase + (size_t)(c0 + 3) * HW];
        out[obase + (size_t)(c0 + 0) * HW] = v.x;
        out[obase + (size_t)(c0 + 1) * HW] = v.y;
        out[obase + (size_t)(c0 + 2) * HW] = v.z;
        out[obase + (size_t)(c0 + 3) * HW] = v.w;
        float d0 = v.x - z0, d1 = v.y - z1, d2 = v.z - z2, d3 = v.w - z3;
        lsum = fmaf(d0, d0, lsum); lsum = fmaf(d1, d1, lsum);
        lsum = fmaf(d2, d2, lsum); lsum = fmaf(d3, d3, lsum);
    }
    #pragma unroll
    for (int off = 32; off; off >>= 1) lsum += __shfl_down(lsum, off);
    __shared__ float red[4];
    if ((tid & 63) == 0) red[tid >> 6] = lsum;
    __syncthreads();
    if (tid == 0)
        partial[blockIdx.x] = red[0] + red[1] + red[2] + red[3];
}

// --- 5: final loss reduction ------------------------------------------------
__global__ void loss_kernel(const float* __restrict__ partial, float* __restrict__ out) {
    float s = partial[threadIdx.x];            // 256 partials
    #pragma unroll
    for (int off = 32; off; off >>= 1) s += __shfl_down(s, off);
    __shared__ float red[4];
    if ((threadIdx.x & 63) == 0) red[threadIdx.x >> 6] = s;
    __syncthreads();
    if (threadIdx.x == 0)
        out[LOSS_OFF] = 1.25f * (red[0] + red[1] + red[2] + red[3]) / 4194304.0f;
}

extern "C" void kernel_launch(void* const* d_in, const int* in_sizes, int n_in,
                              void* d_out, int out_size, void* d_ws, size_t ws_size,
                              hipStream_t stream) {
    const float* z  = (const float*)d_in[0];
    const float* cb = (const float*)d_in[1];
    float* out = (float*)d_out;
    float* partial = (float*)d_ws;   // 1 KB

    prep_kernel<<<2112, 256, 0, stream>>>(z, cb, out);
    argmin_kernel<<<dim3(128, NSLICE), 256, 0, stream>>>(out);
    fixup_kernel<<<NROWS / 8, 256, 0, stream>>>(z, cb, out);
    zq_kernel<<<256, 256, 0, stream>>>(z, cb, out, partial);
    loss_kernel<<<1, 256, 0, stream>>>(partial, out);
}

// Round 6
// 200.126 us; speedup vs baseline: 7.2336x; 1.1773x over previous
//
#include <hip/hip_runtime.h>
#include <cfloat>

// ---------------------------------------------------------------------------
// VectorQuantizer: z (16,256,32,32) f32, codebook (8192,256) f32
// outputs (f32 concat): z_q [4194304], loss [1], idx-as-float [16384]
// Validated semantics (R2-R5): idx = argmin_k fl32(zsq - 2*dot32(z,e_k)),
// lowest-index tie-break; bf16-MFMA coarse top-4 x 8 slices -> 32 cands/row,
// survivors re-scored fp64->fp32.
// R6: candidates stored as packed (qv<<10|1023-local) words; fixup prunes to
// candidates within T=128 qv units (6.1e-5 dot) of the row max -> ~1.3
// survivors/row -> cb gather traffic 512MB -> ~20MB.
// ---------------------------------------------------------------------------

#define NROWS 16384
#define NCODE 8192
#define DIMC  256
#define HW    1024
#define ZQN   4194304

// scratch inside d_out's z_q region (dead before zq_kernel overwrites):
#define ZT_OFF   0         // bf16 z [16384][256] as ushort = 2097152 floats
#define CBT_OFF  2097152   // bf16 codebook [8192][256]     = 1048576 floats
#define ZSQ_OFF  3145728   // 16384 floats
#define CAND_OFF 3162112   // 8 slices * 16384 rows * 4 packed uints
#define LOSS_OFF ZQN
#define IDX_OFF  (ZQN + 1)

#define NSLICE 8
#define PRUNE_T 128u       // qv units: covers d-bin (3.05e-5) + 2x6sigma bf16 err

typedef __attribute__((ext_vector_type(8))) short bf16x8;
typedef __attribute__((ext_vector_type(4))) float f32x4;
typedef __attribute__((ext_vector_type(4))) unsigned int uint4v;

__device__ __forceinline__ unsigned umax(unsigned a, unsigned b) { return a > b ? a : b; }
__device__ __forceinline__ unsigned umin(unsigned a, unsigned b) { return a < b ? a : b; }

__device__ __forceinline__ unsigned short f2bf(float f) {   // RNE
    unsigned u = __float_as_uint(f);
    return (unsigned short)((u + 0x7fffu + ((u >> 16) & 1u)) >> 16);
}

#define GLD_LDS16(gptr, lptr) \
  __builtin_amdgcn_global_load_lds((const __attribute__((address_space(1))) unsigned int*)(const void*)(gptr), \
                                   (__attribute__((address_space(3))) unsigned int*)(lptr), 16, 0, 0)

// --- 1: fused prep: zt transpose+cvt | cbt cvt | zsq ------------------------
__global__ void prep_kernel(const float* __restrict__ z, const float* __restrict__ cb,
                            float* __restrict__ out) {
    int bid = blockIdx.x;
    int tid = threadIdx.x;
    if (bid < 1024) {
        __shared__ unsigned short lds[64 * 65];
        unsigned short* zt = (unsigned short*)(out + ZT_OFF);
        int c0 = (bid & 3) * 64;
        int n0 = (bid >> 2) * 64;
        const float* zb = z + (size_t)(n0 >> 10) * (DIMC * HW) + (n0 & 1023);
        #pragma unroll
        for (int i = 0; i < 4; ++i) {
            int f = tid + i * 256;
            int cl = f >> 4, n4 = f & 15;
            float4 v = *(const float4*)(zb + (size_t)(c0 + cl) * HW + n4 * 4);
            lds[(n4 * 4 + 0) * 65 + cl] = f2bf(v.x);
            lds[(n4 * 4 + 1) * 65 + cl] = f2bf(v.y);
            lds[(n4 * 4 + 2) * 65 + cl] = f2bf(v.z);
            lds[(n4 * 4 + 3) * 65 + cl] = f2bf(v.w);
        }
        __syncthreads();
        #pragma unroll
        for (int i = 0; i < 2; ++i) {
            int f = tid + i * 256;
            int nl = f >> 3, oct = f & 7;
            const unsigned short* p = lds + nl * 65 + oct * 8;
            uint4v u;
            u.x = (unsigned)p[0] | ((unsigned)p[1] << 16);
            u.y = (unsigned)p[2] | ((unsigned)p[3] << 16);
            u.z = (unsigned)p[4] | ((unsigned)p[5] << 16);
            u.w = (unsigned)p[6] | ((unsigned)p[7] << 16);
            *(uint4v*)(zt + (size_t)(n0 + nl) * DIMC + c0 + oct * 8) = u;
        }
    } else if (bid < 2048) {
        unsigned short* cbt = (unsigned short*)(out + CBT_OFF);
        size_t t = (size_t)(bid - 1024) * 256 + tid;
        float4 a = *(const float4*)(cb + t * 8);
        float4 b = *(const float4*)(cb + t * 8 + 4);
        uint4v u;
        u.x = (unsigned)f2bf(a.x) | ((unsigned)f2bf(a.y) << 16);
        u.y = (unsigned)f2bf(a.z) | ((unsigned)f2bf(a.w) << 16);
        u.z = (unsigned)f2bf(b.x) | ((unsigned)f2bf(b.y) << 16);
        u.w = (unsigned)f2bf(b.z) | ((unsigned)f2bf(b.w) << 16);
        *(uint4v*)(cbt + t * 8) = u;
    } else {
        int n = (bid - 2048) * 256 + tid;
        const float* zp = z + (size_t)(n >> 10) * (DIMC * HW) + (n & 1023);
        double s = 0.0;
        for (int c = 0; c < DIMC; ++c) {
            double v = (double)zp[(size_t)c * HW];
            s += v * v;
        }
        out[ZSQ_OFF + n] = (float)s;
    }
}

// --- 2: bf16 MFMA argmin: z-rows in registers, codes streamed ---------------
// grid (128 row-blocks, 8 slices), 256 threads. Block: 128 rows x 1024 codes.
__global__ __launch_bounds__(256, 4)
void argmin_kernel(float* __restrict__ out) {
    __shared__ __align__(16) unsigned short a_s[32 * 256];   // 16 KB code chunk
    const unsigned short* zt  = (const unsigned short*)(out + ZT_OFF);
    const unsigned short* cbt = (const unsigned short*)(out + CBT_OFF);
    unsigned* cand = (unsigned*)(out + CAND_OFF);

    int tid = threadIdx.x;
    int lane = tid & 63;
    int wv = tid >> 6;
    int col = lane & 15, qk = lane >> 4;
    int n0 = blockIdx.x * 128;
    int slice = blockIdx.y;

    // B: this wave's 32 z-rows resident in registers (2 rowfrags x 8 dsteps)
    bf16x8 B[2][8];
    #pragma unroll
    for (int rf = 0; rf < 2; ++rf)
        #pragma unroll
        for (int t = 0; t < 8; ++t)
            B[rf][t] = *(const bf16x8*)(zt + (size_t)(n0 + wv * 32 + rf * 16 + col) * DIMC
                                           + t * 32 + qk * 8);

    // staging source: lane covers (row pair, 16B slot), XOR-swizzled slot
    int rl2 = lane >> 5;
    int jsl = lane & 31;
    const unsigned short* srcb[4];
    #pragma unroll
    for (int c = 0; c < 4; ++c) {
        int rloc = (wv * 4 + c) * 2 + rl2;
        int src16 = jsl ^ (rloc & 7);
        srcb[c] = cbt + ((size_t)slice * 1024 + rloc) * DIMC + src16 * 8;
    }

    unsigned U1[2] = {0, 0}, U2[2] = {0, 0};

    for (int ch = 0; ch < 32; ++ch) {
        __syncthreads();
        #pragma unroll
        for (int c = 0; c < 4; ++c)
            GLD_LDS16(srcb[c] + (size_t)ch * 32 * DIMC, a_s + (wv * 4 + c) * 512);
        __syncthreads();

        f32x4 acc[2][2];
        #pragma unroll
        for (int rf = 0; rf < 2; ++rf)
            #pragma unroll
            for (int cf = 0; cf < 2; ++cf)
                acc[rf][cf] = (f32x4){0.f, 0.f, 0.f, 0.f};
        #pragma unroll
        for (int cf = 0; cf < 2; ++cf) {
            int rloc = cf * 16 + col;
            #pragma unroll
            for (int t = 0; t < 8; ++t) {
                bf16x8 af = *(const bf16x8*)(a_s + rloc * 256
                                             + ((unsigned)((qk + 4 * t) ^ (rloc & 7))) * 8);
                acc[0][cf] = __builtin_amdgcn_mfma_f32_16x16x32_bf16(af, B[0][t], acc[0][cf], 0, 0, 0);
                acc[1][cf] = __builtin_amdgcn_mfma_f32_16x16x32_bf16(af, B[1][t], acc[1][cf], 0, 0, 0);
            }
        }
        #pragma unroll
        for (int rf = 0; rf < 2; ++rf)
            #pragma unroll
            for (int cf = 0; cf < 2; ++cf)
                #pragma unroll
                for (int r = 0; r < 4; ++r) {
                    float s = acc[rf][cf][r];
                    unsigned qv = (unsigned)fmaf(s, 2097152.0f, 131072.0f);
                    unsigned u = (qv << 8) | (255u - (unsigned)((ch << 3) | (cf << 2) | r));
                    unsigned lo = umin(u, U1[rf]);
                    U1[rf] = umax(u, U1[rf]);
                    U2[rf] = umax(lo, U2[rf]);
                }
    }

    // decode to (qv<<10 | 1023-local), merge across qk, store PACKED top-4
    #pragma unroll
    for (int rf = 0; rf < 2; ++rf) {
        unsigned t1 = 255u - (U1[rf] & 255u);
        unsigned c1 = (t1 >> 3) * 32 + ((t1 >> 2) & 1) * 16 + qk * 4 + (t1 & 3);
        unsigned x1 = ((U1[rf] >> 8) << 10) | (1023u - c1);
        unsigned t2 = 255u - (U2[rf] & 255u);
        unsigned c2 = (t2 >> 3) * 32 + ((t2 >> 2) & 1) * 16 + qk * 4 + (t2 & 3);
        unsigned x2 = ((U2[rf] >> 8) << 10) | (1023u - c2);
        unsigned p1 = __shfl_xor(x1, 16);
        unsigned p2 = __shfl_xor(x2, 16);
        unsigned s1 = umax(x1, p1), tm = umin(x1, p1);
        unsigned ym = umax(x2, p2), s4 = umin(x2, p2);
        unsigned s2 = umax(tm, ym), s3 = umin(tm, ym);
        unsigned r1 = umax(s1, __shfl_xor(s4, 32));
        unsigned r2 = umax(s2, __shfl_xor(s3, 32));
        unsigned r3 = umax(s3, __shfl_xor(s2, 32));
        unsigned r4 = umax(s4, __shfl_xor(s1, 32));
        if (qk == 0) {
            int row = wv * 32 + rf * 16 + col;
            uint4v cw; cw.x = r1; cw.y = r2; cw.z = r3; cw.w = r4;
            *(uint4v*)(cand + ((size_t)slice * NROWS + n0 + row) * 4) = cw;
        }
    }
}

// --- 3: prune (coarse-score margin) + fp64 re-score survivors ---------------
// 2048 blocks x 256 threads; block = 8 rows x 32 candidates.
__global__ __launch_bounds__(256, 4)
void fixup_kernel(const float* __restrict__ z, const float* __restrict__ cb,
                  float* __restrict__ out) {
    __shared__ double zd[DIMC * 8];
    __shared__ float zsq_s[8];
    __shared__ unsigned qmx[8];
    __shared__ float dsc[32 * 8];
    __shared__ unsigned cds[32 * 8];
    int tid = threadIdx.x;
    int n0 = blockIdx.x * 8;
    const float* zb = z + (size_t)(n0 >> 10) * (DIMC * HW) + (n0 & 1023);
    int rr = tid & 7;
    #pragma unroll
    for (int i = 0; i < 8; ++i) {
        int c = (tid >> 3) + i * 32;
        zd[c * 8 + rr] = (double)zb[(size_t)c * HW + rr];
    }
    if (tid < 8) { zsq_s[tid] = out[ZSQ_OFF + n0 + tid]; qmx[tid] = 0; }
    int j = tid >> 3, r = tid & 7;
    unsigned w = ((const unsigned*)(out + CAND_OFF))
                 [(((size_t)(j >> 2)) * NROWS + n0 + r) * 4 + (j & 3)];
    unsigned qv = w >> 10;
    unsigned code = (unsigned)((j >> 2) * 1024) + 1023u - (w & 1023u);
    __syncthreads();
    atomicMax(&qmx[r], qv);
    __syncthreads();
    bool live = (qv + PRUNE_T >= qmx[r]);
    float d = FLT_MAX;
    if (live) {
        const float* e = cb + (size_t)code * DIMC;
        double a0 = 0.0, a1 = 0.0, a2 = 0.0, a3 = 0.0;
        for (int c = 0; c < DIMC; c += 16) {
            float4 e0 = *(const float4*)(e + c);
            float4 e1 = *(const float4*)(e + c + 4);
            float4 e2 = *(const float4*)(e + c + 8);
            float4 e3 = *(const float4*)(e + c + 12);
            a0 += zd[(c + 0) * 8 + r] * (double)e0.x + zd[(c + 1) * 8 + r] * (double)e0.y
                + zd[(c + 2) * 8 + r] * (double)e0.z + zd[(c + 3) * 8 + r] * (double)e0.w;
            a1 += zd[(c + 4) * 8 + r] * (double)e1.x + zd[(c + 5) * 8 + r] * (double)e1.y
                + zd[(c + 6) * 8 + r] * (double)e1.z + zd[(c + 7) * 8 + r] * (double)e1.w;
            a2 += zd[(c + 8) * 8 + r] * (double)e2.x + zd[(c + 9) * 8 + r] * (double)e2.y
                + zd[(c + 10) * 8 + r] * (double)e2.z + zd[(c + 11) * 8 + r] * (double)e2.w;
            a3 += zd[(c + 12) * 8 + r] * (double)e3.x + zd[(c + 13) * 8 + r] * (double)e3.y
                + zd[(c + 14) * 8 + r] * (double)e3.z + zd[(c + 15) * 8 + r] * (double)e3.w;
        }
        d = fmaf(-2.0f, (float)((a0 + a1) + (a2 + a3)), zsq_s[r]);
    }
    dsc[j * 8 + r] = d;
    cds[j * 8 + r] = code;
    __syncthreads();
    if (tid < 8) {
        float bd = FLT_MAX; unsigned bi = 0xffffffffu;
        for (int jj = 0; jj < 32; ++jj) {
            float dv = dsc[jj * 8 + tid];
            unsigned k = cds[jj * 8 + tid];
            if (dv < bd || (dv == bd && k < bi)) { bd = dv; bi = k; }
        }
        out[IDX_OFF + n0 + tid] = (float)bi;
    }
}

// --- 4: z_q via LDS-staged codebook rows + loss partials --------------------
__global__ void zq_kernel(const float* __restrict__ z, const float* __restrict__ cb,
                          float* __restrict__ out, float* __restrict__ partial) {
    __shared__ float lds[64 * 256];
    int tid = threadIdx.x;
    int n0 = blockIdx.x * 64;
    {
        int r = tid >> 2, q = tid & 3;
        int code = (int)out[IDX_OFF + n0 + r];
        const float* e = cb + (size_t)code * DIMC + q * 64;
        #pragma unroll
        for (int i = 0; i < 16; ++i) {
            float4 v = *(const float4*)(e + i * 4);
            int c4 = q * 16 + i;
            *(float4*)(lds + r * 256 + ((c4 ^ (r & 7)) * 4)) = v;
        }
    }
    __syncthreads();
    int hwl = tid & 63, g = tid >> 6;
    int b = n0 >> 10, hw0 = n0 & 1023;
    const size_t obase = (size_t)b * (DIMC * HW) + hw0 + hwl;
    float lsum = 0.f;
    #pragma unroll
    for (int i = 0; i < 16; ++i) {
        int c4 = g * 16 + i;
        float4 v = *(const float4*)(lds + hwl * 256 + ((c4 ^ (hwl & 7)) * 4));
        int c0 = c4 * 4;
        float z0 = z[obase + (size_t)(c0 + 0) * HW];
        float z1 = z[obase + (size_t)(c0 + 1) * HW];
        float z2 = z[obase + (size_t)(c0 + 2) * HW];
        float z3 = z[obase + (size_t)(c0 + 3) * HW];
        out[obase + (size_t)(c0 + 0) * HW] = v.x;
        out[obase + (size_t)(c0 + 1) * HW] = v.y;
        out[obase + (size_t)(c0 + 2) * HW] = v.z;
        out[obase + (size_t)(c0 + 3) * HW] = v.w;
        float d0 = v.x - z0, d1 = v.y - z1, d2 = v.z - z2, d3 = v.w - z3;
        lsum = fmaf(d0, d0, lsum); lsum = fmaf(d1, d1, lsum);
        lsum = fmaf(d2, d2, lsum); lsum = fmaf(d3, d3, lsum);
    }
    #pragma unroll
    for (int off = 32; off; off >>= 1) lsum += __shfl_down(lsum, off);
    __shared__ float red[4];
    if ((tid & 63) == 0) red[tid >> 6] = lsum;
    __syncthreads();
    if (tid == 0)
        partial[blockIdx.x] = red[0] + red[1] + red[2] + red[3];
}

// --- 5: final loss reduction ------------------------------------------------
__global__ void loss_kernel(const float* __restrict__ partial, float* __restrict__ out) {
    float s = partial[threadIdx.x];
    #pragma unroll
    for (int off = 32; off; off >>= 1) s += __shfl_down(s, off);
    __shared__ float red[4];
    if ((threadIdx.x & 63) == 0) red[threadIdx.x >> 6] = s;
    __syncthreads();
    if (threadIdx.x == 0)
        out[LOSS_OFF] = 1.25f * (red[0] + red[1] + red[2] + red[3]) / 4194304.0f;
}

extern "C" void kernel_launch(void* const* d_in, const int* in_sizes, int n_in,
                              void* d_out, int out_size, void* d_ws, size_t ws_size,
                              hipStream_t stream) {
    const float* z  = (const float*)d_in[0];
    const float* cb = (const float*)d_in[1];
    float* out = (float*)d_out;
    float* partial = (float*)d_ws;   // 1 KB

    prep_kernel<<<2112, 256, 0, stream>>>(z, cb, out);
    argmin_kernel<<<dim3(128, NSLICE), 256, 0, stream>>>(out);
    fixup_kernel<<<NROWS / 8, 256, 0, stream>>>(z, cb, out);
    zq_kernel<<<256, 256, 0, stream>>>(z, cb, out, partial);
    loss_kernel<<<1, 256, 0, stream>>>(partial, out);
}

// Round 7
// 187.611 us; speedup vs baseline: 7.7161x; 1.0667x over previous
//
#include <hip/hip_runtime.h>
#include <cfloat>

// ---------------------------------------------------------------------------
// VectorQuantizer: z (16,256,32,32) f32, codebook (8192,256) f32
// outputs (f32 concat): z_q [4194304], loss [1], idx-as-float [16384]
// Validated semantics (R2-R6): idx = argmin_k fl32(zsq - 2*dot32(z,e_k)),
// lowest-index tie-break; bf16-MFMA coarse top-4 x 8 slices -> 32 cands/row;
// prune to coarse margin of row max; survivors re-scored fp64->fp32.
// R7: argmin restructured: async double-buffered LDS (1 barrier/chunk,
// prefetch covers the vmcnt drain), 64 z-rows/wave (A-frag reuse 4x),
// tagged-float epilogue (5 VALU/score). Loss folded into zq (atomicAdd).
// ---------------------------------------------------------------------------

#define NROWS 16384
#define NCODE 8192
#define DIMC  256
#define HW    1024
#define ZQN   4194304

// scratch inside d_out's z_q region (dead before zq_kernel overwrites):
#define ZT_OFF   0         // bf16 z [16384][256] as ushort = 2097152 floats
#define CBT_OFF  2097152   // bf16 codebook [8192][256]     = 1048576 floats
#define ZSQ_OFF  3145728   // 16384 floats
#define CAND_OFF 3162112   // 8 slices * 16384 rows * 4 packed uints
#define LOSS_OFF ZQN
#define IDX_OFF  (ZQN + 1)

#define NSLICE 8
#define PRUNE_T 4300u      // key units (8 float-ulps each, worst 1.49e-8 dot):
                           // covers d-bin 3.05e-5 + 2x6sigma bf16 + tag-quant

typedef __attribute__((ext_vector_type(8))) short bf16x8;
typedef __attribute__((ext_vector_type(4))) float f32x4;
typedef __attribute__((ext_vector_type(4))) unsigned int uint4v;

__device__ __forceinline__ unsigned umax(unsigned a, unsigned b) { return a > b ? a : b; }
__device__ __forceinline__ unsigned umin(unsigned a, unsigned b) { return a < b ? a : b; }

__device__ __forceinline__ unsigned short f2bf(float f) {   // RNE
    unsigned u = __float_as_uint(f);
    return (unsigned short)((u + 0x7fffu + ((u >> 16) & 1u)) >> 16);
}

#define GLD_LDS16(gptr, lptr) \
  __builtin_amdgcn_global_load_lds((const __attribute__((address_space(1))) unsigned int*)(const void*)(gptr), \
                                   (__attribute__((address_space(3))) unsigned int*)(lptr), 16, 0, 0)

// --- 1: fused prep: zt transpose+cvt | cbt cvt | zsq | loss zero ------------
__global__ void prep_kernel(const float* __restrict__ z, const float* __restrict__ cb,
                            float* __restrict__ out) {
    int bid = blockIdx.x;
    int tid = threadIdx.x;
    if (bid < 1024) {
        __shared__ unsigned short lds[64 * 65];
        unsigned short* zt = (unsigned short*)(out + ZT_OFF);
        int c0 = (bid & 3) * 64;
        int n0 = (bid >> 2) * 64;
        const float* zb = z + (size_t)(n0 >> 10) * (DIMC * HW) + (n0 & 1023);
        #pragma unroll
        for (int i = 0; i < 4; ++i) {
            int f = tid + i * 256;
            int cl = f >> 4, n4 = f & 15;
            float4 v = *(const float4*)(zb + (size_t)(c0 + cl) * HW + n4 * 4);
            lds[(n4 * 4 + 0) * 65 + cl] = f2bf(v.x);
            lds[(n4 * 4 + 1) * 65 + cl] = f2bf(v.y);
            lds[(n4 * 4 + 2) * 65 + cl] = f2bf(v.z);
            lds[(n4 * 4 + 3) * 65 + cl] = f2bf(v.w);
        }
        __syncthreads();
        #pragma unroll
        for (int i = 0; i < 2; ++i) {
            int f = tid + i * 256;
            int nl = f >> 3, oct = f & 7;
            const unsigned short* p = lds + nl * 65 + oct * 8;
            uint4v u;
            u.x = (unsigned)p[0] | ((unsigned)p[1] << 16);
            u.y = (unsigned)p[2] | ((unsigned)p[3] << 16);
            u.z = (unsigned)p[4] | ((unsigned)p[5] << 16);
            u.w = (unsigned)p[6] | ((unsigned)p[7] << 16);
            *(uint4v*)(zt + (size_t)(n0 + nl) * DIMC + c0 + oct * 8) = u;
        }
    } else if (bid < 2048) {
        unsigned short* cbt = (unsigned short*)(out + CBT_OFF);
        size_t t = (size_t)(bid - 1024) * 256 + tid;
        float4 a = *(const float4*)(cb + t * 8);
        float4 b = *(const float4*)(cb + t * 8 + 4);
        uint4v u;
        u.x = (unsigned)f2bf(a.x) | ((unsigned)f2bf(a.y) << 16);
        u.y = (unsigned)f2bf(a.z) | ((unsigned)f2bf(a.w) << 16);
        u.z = (unsigned)f2bf(b.x) | ((unsigned)f2bf(b.y) << 16);
        u.w = (unsigned)f2bf(b.z) | ((unsigned)f2bf(b.w) << 16);
        *(uint4v*)(cbt + t * 8) = u;
        if (bid == 1024 && tid == 0) out[LOSS_OFF] = 0.0f;
    } else {
        int n = (bid - 2048) * 256 + tid;
        const float* zp = z + (size_t)(n >> 10) * (DIMC * HW) + (n & 1023);
        double s = 0.0;
        for (int c = 0; c < DIMC; ++c) {
            double v = (double)zp[(size_t)c * HW];
            s += v * v;
        }
        out[ZSQ_OFF + n] = (float)s;
    }
}

// --- 2: bf16 MFMA argmin: 64 z-rows/wave in regs, async dbuf code stream ----
// grid (64 row-blocks, 8 slices), 256 threads. Block: 256 rows x 1024 codes.
__global__ __launch_bounds__(256, 2)
void argmin_kernel(float* __restrict__ out) {
    __shared__ __align__(16) unsigned short a_s[2 * 32 * 256];   // 32 KB dbuf
    const unsigned short* zt  = (const unsigned short*)(out + ZT_OFF);
    const unsigned short* cbt = (const unsigned short*)(out + CBT_OFF);
    unsigned* cand = (unsigned*)(out + CAND_OFF);

    int tid = threadIdx.x;
    int lane = tid & 63;
    int wv = tid >> 6;
    int col = lane & 15, qk = lane >> 4;
    int n0 = blockIdx.x * 256;
    int slice = blockIdx.y;

    // B: wave's 64 z-rows resident in registers (4 rowfrags x 8 dsteps)
    bf16x8 B[4][8];
    #pragma unroll
    for (int rf = 0; rf < 4; ++rf)
        #pragma unroll
        for (int t = 0; t < 8; ++t)
            B[rf][t] = *(const bf16x8*)(zt + (size_t)(n0 + wv * 64 + rf * 16 + col) * DIMC
                                           + t * 32 + qk * 8);

    // staging sources: lane covers (row pair, 16B slot), XOR-swizzled slot
    int rl2 = lane >> 5;
    int jsl = lane & 31;
    const unsigned short* srcb[4];
    #pragma unroll
    for (int c = 0; c < 4; ++c) {
        int rloc = (wv * 4 + c) * 2 + rl2;
        int src16 = jsl ^ (rloc & 7);
        srcb[c] = cbt + ((size_t)slice * 1024 + rloc) * DIMC + src16 * 8;
    }

    unsigned U1[4] = {0, 0, 0, 0}, U2[4] = {0, 0, 0, 0};

    // prologue: stage chunk 0 into buffer 0
    #pragma unroll
    for (int c = 0; c < 4; ++c)
        GLD_LDS16(srcb[c], a_s + (wv * 4 + c) * 512);

    for (int ch = 0; ch < 32; ++ch) {
        __syncthreads();   // drains GLD(ch) (issued one compute-phase ago);
                           // proves all waves done reading the other buffer
        if (ch < 31) {
            const size_t off = (size_t)(ch + 1) * 32 * DIMC;
            unsigned short* dst = a_s + ((ch + 1) & 1) * 8192;
            #pragma unroll
            for (int c = 0; c < 4; ++c)
                GLD_LDS16(srcb[c] + off, dst + (wv * 4 + c) * 512);
        }
        const unsigned short* as = a_s + (ch & 1) * 8192;

        f32x4 acc[4][2];
        #pragma unroll
        for (int rf = 0; rf < 4; ++rf)
            #pragma unroll
            for (int cf = 0; cf < 2; ++cf)
                acc[rf][cf] = (f32x4){0.f, 0.f, 0.f, 0.f};
        #pragma unroll
        for (int cf = 0; cf < 2; ++cf) {
            int rloc = cf * 16 + col;
            #pragma unroll
            for (int t = 0; t < 8; ++t) {
                bf16x8 af = *(const bf16x8*)(as + rloc * 256
                                             + ((unsigned)((qk + 4 * t) ^ (rloc & 7))) * 8);
                acc[0][cf] = __builtin_amdgcn_mfma_f32_16x16x32_bf16(af, B[0][t], acc[0][cf], 0, 0, 0);
                acc[1][cf] = __builtin_amdgcn_mfma_f32_16x16x32_bf16(af, B[1][t], acc[1][cf], 0, 0, 0);
                acc[2][cf] = __builtin_amdgcn_mfma_f32_16x16x32_bf16(af, B[2][t], acc[2][cf], 0, 0, 0);
                acc[3][cf] = __builtin_amdgcn_mfma_f32_16x16x32_bf16(af, B[3][t], acc[3][cf], 0, 0, 0);
            }
        }
        // epilogue: tagged-float pack (monotonic bits, tag in low 8), top-2
        unsigned tb = 255u - ((unsigned)ch << 3);
        #pragma unroll
        for (int cf = 0; cf < 2; ++cf)
            #pragma unroll
            for (int rf = 0; rf < 4; ++rf)
                #pragma unroll
                for (int r = 0; r < 4; ++r) {
                    unsigned bits = __float_as_uint(
                        fmaf(acc[rf][cf][r], 2097152.0f, 131072.0f));
                    unsigned u = (bits & 0xFFFFFF00u) | (tb - (unsigned)((cf << 2) + r));
                    unsigned lo = umin(u, U1[rf]);
                    U1[rf] = umax(u, U1[rf]);
                    U2[rf] = umax(lo, U2[rf]);
                }
    }

    // decode to (key22<<10 | 1023-local), cross-qk merge top-4, store packed
    #pragma unroll
    for (int rf = 0; rf < 4; ++rf) {
        unsigned t1 = 255u - (U1[rf] & 255u);
        unsigned c1 = (t1 >> 3) * 32 + ((t1 >> 2) & 1) * 16 + qk * 4 + (t1 & 3);
        unsigned x1 = ((((U1[rf] & 0xFFFFFF00u) - 0x47000000u) >> 3) << 10) | (1023u - c1);
        unsigned t2 = 255u - (U2[rf] & 255u);
        unsigned c2 = (t2 >> 3) * 32 + ((t2 >> 2) & 1) * 16 + qk * 4 + (t2 & 3);
        unsigned x2 = ((((U2[rf] & 0xFFFFFF00u) - 0x47000000u) >> 3) << 10) | (1023u - c2);
        unsigned p1 = __shfl_xor(x1, 16);
        unsigned p2 = __shfl_xor(x2, 16);
        unsigned s1 = umax(x1, p1), tm = umin(x1, p1);
        unsigned ym = umax(x2, p2), s4 = umin(x2, p2);
        unsigned s2 = umax(tm, ym), s3 = umin(tm, ym);
        unsigned r1 = umax(s1, __shfl_xor(s4, 32));
        unsigned r2 = umax(s2, __shfl_xor(s3, 32));
        unsigned r3 = umax(s3, __shfl_xor(s2, 32));
        unsigned r4 = umax(s4, __shfl_xor(s1, 32));
        if (qk == 0) {
            int row = wv * 64 + rf * 16 + col;
            uint4v cw; cw.x = r1; cw.y = r2; cw.z = r3; cw.w = r4;
            *(uint4v*)(cand + ((size_t)slice * NROWS + n0 + row) * 4) = cw;
        }
    }
}

// --- 3: prune (coarse-key margin) + fp64 re-score survivors -----------------
// 2048 blocks x 256 threads; block = 8 rows x 32 candidates.
__global__ __launch_bounds__(256, 4)
void fixup_kernel(const float* __restrict__ z, const float* __restrict__ cb,
                  float* __restrict__ out) {
    __shared__ double zd[DIMC * 8];
    __shared__ float zsq_s[8];
    __shared__ unsigned qmx[8];
    __shared__ float dsc[32 * 8];
    __shared__ unsigned cds[32 * 8];
    int tid = threadIdx.x;
    int n0 = blockIdx.x * 8;
    const float* zb = z + (size_t)(n0 >> 10) * (DIMC * HW) + (n0 & 1023);
    int rr = tid & 7;
    #pragma unroll
    for (int i = 0; i < 8; ++i) {
        int c = (tid >> 3) + i * 32;
        zd[c * 8 + rr] = (double)zb[(size_t)c * HW + rr];
    }
    if (tid < 8) { zsq_s[tid] = out[ZSQ_OFF + n0 + tid]; qmx[tid] = 0; }
    int j = tid >> 3, r = tid & 7;
    unsigned w = ((const unsigned*)(out + CAND_OFF))
                 [(((size_t)(j >> 2)) * NROWS + n0 + r) * 4 + (j & 3)];
    unsigned qv = w >> 10;
    unsigned code = (unsigned)((j >> 2) * 1024) + 1023u - (w & 1023u);
    __syncthreads();
    atomicMax(&qmx[r], qv);
    __syncthreads();
    bool live = (qv + PRUNE_T >= qmx[r]);
    float d = FLT_MAX;
    if (live) {
        const float* e = cb + (size_t)code * DIMC;
        double a0 = 0.0, a1 = 0.0, a2 = 0.0, a3 = 0.0;
        for (int c = 0; c < DIMC; c += 16) {
            float4 e0 = *(const float4*)(e + c);
            float4 e1 = *(const float4*)(e + c + 4);
            float4 e2 = *(const float4*)(e + c + 8);
            float4 e3 = *(const float4*)(e + c + 12);
            a0 += zd[(c + 0) * 8 + r] * (double)e0.x + zd[(c + 1) * 8 + r] * (double)e0.y
                + zd[(c + 2) * 8 + r] * (double)e0.z + zd[(c + 3) * 8 + r] * (double)e0.w;
            a1 += zd[(c + 4) * 8 + r] * (double)e1.x + zd[(c + 5) * 8 + r] * (double)e1.y
                + zd[(c + 6) * 8 + r] * (double)e1.z + zd[(c + 7) * 8 + r] * (double)e1.w;
            a2 += zd[(c + 8) * 8 + r] * (double)e2.x + zd[(c + 9) * 8 + r] * (double)e2.y
                + zd[(c + 10) * 8 + r] * (double)e2.z + zd[(c + 11) * 8 + r] * (double)e2.w;
            a3 += zd[(c + 12) * 8 + r] * (double)e3.x + zd[(c + 13) * 8 + r] * (double)e3.y
                + zd[(c + 14) * 8 + r] * (double)e3.z + zd[(c + 15) * 8 + r] * (double)e3.w;
        }
        d = fmaf(-2.0f, (float)((a0 + a1) + (a2 + a3)), zsq_s[r]);
    }
    dsc[j * 8 + r] = d;
    cds[j * 8 + r] = code;
    __syncthreads();
    if (tid < 8) {
        float bd = FLT_MAX; unsigned bi = 0xffffffffu;
        for (int jj = 0; jj < 32; ++jj) {
            float dv = dsc[jj * 8 + tid];
            unsigned k = cds[jj * 8 + tid];
            if (dv < bd || (dv == bd && k < bi)) { bd = dv; bi = k; }
        }
        out[IDX_OFF + n0 + tid] = (float)bi;
    }
}

// --- 4: z_q via LDS-staged codebook rows + fused loss (atomicAdd) -----------
__global__ void zq_kernel(const float* __restrict__ z, const float* __restrict__ cb,
                          float* __restrict__ out) {
    __shared__ float lds[64 * 256];
    int tid = threadIdx.x;
    int n0 = blockIdx.x * 64;
    {
        int r = tid >> 2, q = tid & 3;
        int code = (int)out[IDX_OFF + n0 + r];
        const float* e = cb + (size_t)code * DIMC + q * 64;
        #pragma unroll
        for (int i = 0; i < 16; ++i) {
            float4 v = *(const float4*)(e + i * 4);
            int c4 = q * 16 + i;
            *(float4*)(lds + r * 256 + ((c4 ^ (r & 7)) * 4)) = v;
        }
    }
    __syncthreads();
    int hwl = tid & 63, g = tid >> 6;
    int b = n0 >> 10, hw0 = n0 & 1023;
    const size_t obase = (size_t)b * (DIMC * HW) + hw0 + hwl;
    float lsum = 0.f;
    #pragma unroll
    for (int i = 0; i < 16; ++i) {
        int c4 = g * 16 + i;
        float4 v = *(const float4*)(lds + hwl * 256 + ((c4 ^ (hwl & 7)) * 4));
        int c0 = c4 * 4;
        float z0 = z[obase + (size_t)(c0 + 0) * HW];
        float z1 = z[obase + (size_t)(c0 + 1) * HW];
        float z2 = z[obase + (size_t)(c0 + 2) * HW];
        float z3 = z[obase + (size_t)(c0 + 3) * HW];
        out[obase + (size_t)(c0 + 0) * HW] = v.x;
        out[obase + (size_t)(c0 + 1) * HW] = v.y;
        out[obase + (size_t)(c0 + 2) * HW] = v.z;
        out[obase + (size_t)(c0 + 3) * HW] = v.w;
        float d0 = v.x - z0, d1 = v.y - z1, d2 = v.z - z2, d3 = v.w - z3;
        lsum = fmaf(d0, d0, lsum); lsum = fmaf(d1, d1, lsum);
        lsum = fmaf(d2, d2, lsum); lsum = fmaf(d3, d3, lsum);
    }
    #pragma unroll
    for (int off = 32; off; off >>= 1) lsum += __shfl_down(lsum, off);
    __shared__ float red[4];
    if ((tid & 63) == 0) red[tid >> 6] = lsum;
    __syncthreads();
    if (tid == 0)
        atomicAdd(out + LOSS_OFF,
                  (red[0] + red[1] + red[2] + red[3]) * (1.25f / 4194304.0f));
}

extern "C" void kernel_launch(void* const* d_in, const int* in_sizes, int n_in,
                              void* d_out, int out_size, void* d_ws, size_t ws_size,
                              hipStream_t stream) {
    const float* z  = (const float*)d_in[0];
    const float* cb = (const float*)d_in[1];
    float* out = (float*)d_out;

    prep_kernel<<<2112, 256, 0, stream>>>(z, cb, out);
    argmin_kernel<<<dim3(64, NSLICE), 256, 0, stream>>>(out);
    fixup_kernel<<<NROWS / 8, 256, 0, stream>>>(z, cb, out);
    zq_kernel<<<256, 256, 0, stream>>>(z, cb, out);
}